// Round 4
// baseline (8958.175 us; speedup 1.0000x reference)
//
#include <hip/hip_runtime.h>
#include <hip/hip_bf16.h>

#define NFEAT 256
#define NHID  128
#define NCLASS 40

typedef __attribute__((ext_vector_type(8))) short short8;
typedef __attribute__((ext_vector_type(4))) float float4v;

__device__ __forceinline__ unsigned short f2bf(float f) {
    union { float f; unsigned u; } v; v.f = f;
    unsigned r = v.u + 0x7fff + ((v.u >> 16) & 1);   // RNE
    return (unsigned short)(r >> 16);
}
__device__ __forceinline__ float bflo(unsigned u) { return __uint_as_float(u << 16); }
__device__ __forceinline__ float bfhi(unsigned u) { return __uint_as_float(u & 0xffff0000u); }
__device__ __forceinline__ unsigned packbf(float a, float b) {
    return (unsigned)f2bf(a) | ((unsigned)f2bf(b) << 16);
}

// ---------------- degree ----------------
__global__ void deg_count(const int* __restrict__ rows, int* __restrict__ deg, int E) {
    int e = blockIdx.x * blockDim.x + threadIdx.x;
    if (e < E) atomicAdd(&deg[rows[e]], 1);
}

__global__ void inv_deg(const int* __restrict__ deg, float* __restrict__ inv, int N) {
    int i = blockIdx.x * blockDim.x + threadIdx.x;
    if (i < N) inv[i] = 1.0f / ((float)deg[i] + 1.0f);
}

// ---------------- row_ptr build: block sums -> parallel scan -> final scan ----------------
__global__ void block_sums(const int* __restrict__ deg, int* __restrict__ bsum, int N) {
    __shared__ int s[1024];
    int i = blockIdx.x * 1024 + threadIdx.x;
    s[threadIdx.x] = (i < N) ? deg[i] : 0;
    __syncthreads();
    for (int off = 512; off; off >>= 1) {
        if (threadIdx.x < off) s[threadIdx.x] += s[threadIdx.x + off];
        __syncthreads();
    }
    if (threadIdx.x == 0) bsum[blockIdx.x] = s[0];
}

// single-block exclusive scan (n <= 1024), in-place safe; total -> *total
__global__ void excl_scan(int* __restrict__ data, int* __restrict__ total, int n) {
    __shared__ int s[1024];
    int t = threadIdx.x;
    int v = (t < n) ? data[t] : 0;
    s[t] = v;
    __syncthreads();
    for (int off = 1; off < 1024; off <<= 1) {
        int tmp = (t >= off) ? s[t - off] : 0;
        __syncthreads();
        s[t] += tmp;
        __syncthreads();
    }
    if (t < n) data[t] = s[t] - v;        // exclusive
    if (total && t == n - 1) *total = s[t];
}

__global__ void scan_final(const int* __restrict__ deg, const int* __restrict__ bsum,
                           int* __restrict__ row_ptr, int N) {
    __shared__ int s[1024];
    int t = threadIdx.x;
    int i = blockIdx.x * 1024 + t;
    int v = (i < N) ? deg[i] : 0;
    s[t] = v;
    __syncthreads();
    for (int off = 1; off < 1024; off <<= 1) {
        int tmp = (t >= off) ? s[t - off] : 0;
        __syncthreads();
        s[t] += tmp;
        __syncthreads();
    }
    if (i < N) row_ptr[i] = bsum[blockIdx.x] + s[t] - v;
}

// ---------------- hierarchical binning (amplification-free CSR build) ----------------
// bucket bases come free from row_ptr: base(b) = row_ptr[bucket_start_row].
__global__ void init_cursors(const int* __restrict__ row_ptr, int* __restrict__ cur8,
                             int* __restrict__ cur64, int N) {
    int t = threadIdx.x;
    if (t < 8)  cur8[t]  = row_ptr[min(t << 14, N)];
    if (t < 64) cur64[t] = row_ptr[min(t << 11, N)];
}

// wave-chunked append: one atomic + contiguous chunk write per (wave, bucket)
__device__ __forceinline__ void chunk_append(int r, int c, int bucket, bool valid,
                                             int* __restrict__ cursors, int2* __restrict__ out) {
    int lane = threadIdx.x & 63;
    unsigned long long remaining = __ballot(valid);
    while (remaining) {
        int leader = __ffsll(remaining) - 1;
        int target = __shfl(bucket, leader);
        unsigned long long m = __ballot(valid && bucket == target);
        if (valid && bucket == target) {
            int cnt = __popcll(m);
            int base = 0;
            if (lane == leader) base = atomicAdd(&cursors[target], cnt);
            base = __shfl(base, leader);
            int off = __popcll(m & ((1ull << lane) - 1ull));
            out[base + off] = make_int2(r, c);
        }
        remaining &= ~m;
    }
}

__global__ void bin_pass_a(const int* __restrict__ rows, const int* __restrict__ cols,
                           int* __restrict__ cur8, int2* __restrict__ bin8, int E) {
    int e = blockIdx.x * blockDim.x + threadIdx.x;
    bool valid = e < E;
    int r = valid ? rows[e] : 0;
    int c = valid ? cols[e] : 0;
    chunk_append(r, c, valid ? (r >> 14) : -1, valid, cur8, bin8);
}

__global__ void bin_pass_b(const int2* __restrict__ bin8, int* __restrict__ cur64,
                           int2* __restrict__ bin64, int E) {
    int e = blockIdx.x * blockDim.x + threadIdx.x;
    bool valid = e < E;
    int2 rc = valid ? bin8[e] : make_int2(0, 0);
    chunk_append(rc.x, rc.y, valid ? (rc.x >> 11) : -1, valid, cur64, bin64);
}

// final fill: one workgroup owns 512 rows (64KB csr window) -> all writes to a line
// come from one CU -> lines fill in local L2, write back once.
__global__ __launch_bounds__(256) void fill_csr_win(const int2* __restrict__ bin64,
                                                    const int* __restrict__ row_ptr,
                                                    int* __restrict__ csr_cols, int N) {
    __shared__ int lcur[512];
    int w = blockIdx.x;
    int r0 = w << 9;
    for (int i = threadIdx.x; i < 512; i += 256) {
        int r = r0 + i;
        lcur[i] = (r < N) ? row_ptr[r] : 0;
    }
    __syncthreads();
    int sb = w >> 2;                       // 2048-row parent sub-bucket
    int base = row_ptr[min(sb << 11, N)];
    int endp = row_ptr[min((sb + 1) << 11, N)];
    for (int e = base + (int)threadIdx.x; e < endp; e += 256) {
        int2 rc = bin64[e];
        if ((rc.x >> 9) == w) {
            int idx = atomicAdd(&lcur[rc.x & 511], 1);
            csr_cols[idx] = rc.y;
        }
    }
}

// ---------------- fp32 -> bf16 conversion of x ----------------
__global__ void conv_bf16(const float* __restrict__ in, unsigned short* __restrict__ out, long long n4) {
    long long i = (long long)blockIdx.x * blockDim.x + threadIdx.x;
    if (i >= n4) return;
    float4 v = *reinterpret_cast<const float4*>(&in[i * 4]);
    ushort4 o;
    o.x = f2bf(v.x); o.y = f2bf(v.y); o.z = f2bf(v.z); o.w = f2bf(v.w);
    *reinterpret_cast<ushort4*>(&out[i * 4]) = o;
}

// ---------------- weight repack to bf16 K-panel layout: Wp[k0/32][o(256)][k(32)] ----------------
__global__ void repack_W1p(const float* __restrict__ W1, unsigned short* __restrict__ Wp) {
    int o = blockIdx.x;       // 0..255
    int k = threadIdx.x;      // 0..255
    float v = (o < 128) ? W1[o * 512 + k] : W1[(o - 128) * 512 + 256 + k];
    Wp[(size_t)(k >> 5) * 256 * 32 + o * 32 + (k & 31)] = f2bf(v);
}

__global__ void repack_W2p(const float* __restrict__ W2, unsigned short* __restrict__ Wp) {
    int o = blockIdx.x;       // 0..255
    int k = threadIdx.x;      // 0..127
    float v = (o < 128) ? W2[o * 256 + k] : W2[(o - 128) * 256 + 128 + k];
    Wp[(size_t)(k >> 5) * 256 * 32 + o * 32 + (k & 31)] = f2bf(v);
}

// ---------------- bf16 MFMA GEMM: P[M x 256] = Xb[M x K] @ W (packed) ----------------
#define LDK 40
__global__ __launch_bounds__(256) void gemm_mfma(const unsigned short* __restrict__ Xb,
                                                 const unsigned short* __restrict__ Wp,
                                                 unsigned short* __restrict__ P,
                                                 int M, int K) {
    __shared__ unsigned short sA[128][LDK];
    __shared__ unsigned short sB[128][LDK];
    const int t    = threadIdx.x;
    const int lane = t & 63;
    const int wave = t >> 6;
    const int m0 = blockIdx.x * 128;
    const int n0 = blockIdx.y * 128;
    const int wm = (wave >> 1) * 64;
    const int wn = (wave & 1) * 64;

    const int lrow = t >> 2;
    const int lk   = (t & 3) * 8;
    const int r15  = lane & 15;
    const int k8   = (lane >> 4) * 8;

    float4v acc[4][4] = {{{0.f,0.f,0.f,0.f}}};

    for (int k0 = 0; k0 < K; k0 += 32) {
        #pragma unroll
        for (int it = 0; it < 2; ++it) {
            int r  = lrow + it * 64;
            int gm = m0 + r;
            float4 v = make_float4(0.f, 0.f, 0.f, 0.f);
            if (gm < M) v = *reinterpret_cast<const float4*>(&Xb[(size_t)gm * K + k0 + lk]);
            *reinterpret_cast<float4*>(&sA[r][lk]) = v;
        }
        const unsigned short* pan = Wp + ((size_t)(k0 >> 5) * 256 + n0) * 32;
        #pragma unroll
        for (int it = 0; it < 2; ++it) {
            int r = lrow + it * 64;
            float4 v = *reinterpret_cast<const float4*>(&pan[(size_t)r * 32 + lk]);
            *reinterpret_cast<float4*>(&sB[r][lk]) = v;
        }
        __syncthreads();

        short8 aF[4], bF[4];
        #pragma unroll
        for (int i = 0; i < 4; ++i)
            aF[i] = *reinterpret_cast<const short8*>(&sA[wm + i * 16 + r15][k8]);
        #pragma unroll
        for (int j = 0; j < 4; ++j)
            bF[j] = *reinterpret_cast<const short8*>(&sB[wn + j * 16 + r15][k8]);
        #pragma unroll
        for (int i = 0; i < 4; ++i)
            #pragma unroll
            for (int j = 0; j < 4; ++j)
                acc[i][j] = __builtin_amdgcn_mfma_f32_16x16x32_bf16(aF[i], bF[j], acc[i][j], 0, 0, 0);
        __syncthreads();
    }

    #pragma unroll
    for (int i = 0; i < 4; ++i) {
        #pragma unroll
        for (int r = 0; r < 4; ++r) {
            int row = m0 + wm + i * 16 + (lane >> 4) * 4 + r;
            if (row < M) {
                #pragma unroll
                for (int j = 0; j < 4; ++j)
                    P[(size_t)row * 256 + n0 + wn + j * 16 + r15] = f2bf(acc[i][j][r]);
            }
        }
    }
}

// ---------------- gather-aggregate + combine + relu: one wave per node ----------------
// 16-lane groups: group g handles neighbors beg+g, beg+g+4, ...; lane l16 covers 8 features.
// One dwordx4 load = 4 neighbors x 256B = 1KB per wave-instruction.
__global__ __launch_bounds__(256) void gather_combine(const unsigned short* __restrict__ P,
                                                      const int* __restrict__ row_ptr,
                                                      const int* __restrict__ csr_cols,
                                                      const float* __restrict__ invdeg,
                                                      unsigned short* __restrict__ H, int N) {
    int node = (blockIdx.x * blockDim.x + threadIdx.x) >> 6;
    if (node >= N) return;
    int lane = threadIdx.x & 63;
    int grp  = lane >> 4;
    int l16  = lane & 15;
    int beg = row_ptr[node], end = row_ptr[node + 1];

    float a0=0,a1=0,a2=0,a3=0,a4=0,a5=0,a6=0,a7=0;
    for (int p = beg + grp; p < end; p += 4) {
        int c = csr_cols[p];
        uint4 u = *reinterpret_cast<const uint4*>(&P[(size_t)c * 256 + 128 + l16 * 8]);
        a0 += bflo(u.x); a1 += bfhi(u.x);
        a2 += bflo(u.y); a3 += bfhi(u.y);
        a4 += bflo(u.z); a5 += bfhi(u.z);
        a6 += bflo(u.w); a7 += bfhi(u.w);
    }
    // reduce across the 4 groups (xor 16, then 32)
    a0 += __shfl_xor(a0, 16); a1 += __shfl_xor(a1, 16);
    a2 += __shfl_xor(a2, 16); a3 += __shfl_xor(a3, 16);
    a4 += __shfl_xor(a4, 16); a5 += __shfl_xor(a5, 16);
    a6 += __shfl_xor(a6, 16); a7 += __shfl_xor(a7, 16);
    a0 += __shfl_xor(a0, 32); a1 += __shfl_xor(a1, 32);
    a2 += __shfl_xor(a2, 32); a3 += __shfl_xor(a3, 32);
    a4 += __shfl_xor(a4, 32); a5 += __shfl_xor(a5, 32);
    a6 += __shfl_xor(a6, 32); a7 += __shfl_xor(a7, 32);

    if (grp == 0) {
        float id = invdeg[node];
        uint4 us = *reinterpret_cast<const uint4*>(&P[(size_t)node * 256 + l16 * 8]);
        float h0 = fmaxf(fmaf(a0, id, bflo(us.x)), 0.f);
        float h1 = fmaxf(fmaf(a1, id, bfhi(us.x)), 0.f);
        float h2 = fmaxf(fmaf(a2, id, bflo(us.y)), 0.f);
        float h3 = fmaxf(fmaf(a3, id, bfhi(us.y)), 0.f);
        float h4 = fmaxf(fmaf(a4, id, bflo(us.z)), 0.f);
        float h5 = fmaxf(fmaf(a5, id, bfhi(us.z)), 0.f);
        float h6 = fmaxf(fmaf(a6, id, bflo(us.w)), 0.f);
        float h7 = fmaxf(fmaf(a7, id, bfhi(us.w)), 0.f);
        uint4 o;
        o.x = packbf(h0, h1); o.y = packbf(h2, h3);
        o.z = packbf(h4, h5); o.w = packbf(h6, h7);
        *reinterpret_cast<uint4*>(&H[(size_t)node * 128 + l16 * 8]) = o;
    }
}

// ---------------- MLP head + log_softmax: one wave per node ----------------
__global__ __launch_bounds__(256) void mlp_logsoftmax(const unsigned short* __restrict__ H,
                                                      const float* __restrict__ Wm,
                                                      const float* __restrict__ bm,
                                                      float* __restrict__ out, int N) {
    __shared__ float sh[4][128];
    const int w    = threadIdx.x >> 6;
    const int lane = threadIdx.x & 63;
    const int n    = blockIdx.x * 4 + w;
    if (n < N) {
        unsigned u = *reinterpret_cast<const unsigned*>(&H[(size_t)n * 128 + lane * 2]);
        sh[w][lane * 2 + 0] = bflo(u);
        sh[w][lane * 2 + 1] = bfhi(u);
    }
    __syncthreads();
    if (n >= N) return;

    float logit = -1e30f;
    if (lane < NCLASS) {
        float acc = bm[lane];
        const float* wrow = &Wm[lane * 128];
        #pragma unroll 8
        for (int k = 0; k < 128; ++k) acc += sh[w][k] * wrow[k];
        logit = acc;
    }
    float m = logit;
    #pragma unroll
    for (int off = 32; off; off >>= 1) m = fmaxf(m, __shfl_xor(m, off));
    float e = (lane < NCLASS) ? __expf(logit - m) : 0.f;
    float s = e;
    #pragma unroll
    for (int off = 32; off; off >>= 1) s += __shfl_xor(s, off);
    if (lane < NCLASS) out[(size_t)n * NCLASS + lane] = logit - m - __logf(s);
}

extern "C" void kernel_launch(void* const* d_in, const int* in_sizes, int n_in,
                              void* d_out, int out_size, void* d_ws, size_t ws_size,
                              hipStream_t stream) {
    const float* x    = (const float*)d_in[0];
    const float* W1   = (const float*)d_in[1];
    const float* W2   = (const float*)d_in[2];
    const float* mlpW = (const float*)d_in[3];
    const float* mlpb = (const float*)d_in[4];
    const int*   rows = (const int*)d_in[5];
    const int*   cols = (const int*)d_in[6];

    const int N = in_sizes[0] / NFEAT;   // 100000
    const int E = in_sizes[5];           // 3200000

    char* ws = (char*)d_ws;
    size_t off = 0;
    auto alloc = [&](size_t bytes) -> void* {
        void* p = ws + off;
        off = (off + bytes + 255) & ~(size_t)255;
        return p;
    };
    unsigned short* Xb  = (unsigned short*)alloc((size_t)N * 256 * 2);
    unsigned short* P   = (unsigned short*)alloc((size_t)N * 256 * 2);
    unsigned short* H   = (unsigned short*)alloc((size_t)N * 128 * 2);
    int*   DEG    = (int*)  alloc((size_t)N * 4);
    float* INV    = (float*)alloc((size_t)N * 4);
    int*   ROWP   = (int*)  alloc((size_t)(N + 1) * 4);
    int*   CSRC   = (int*)  alloc((size_t)E * 4);
    int2*  BIN8   = (int2*) alloc((size_t)E * 8);
    int2*  BIN64  = (int2*) alloc((size_t)E * 8);
    int*   BSUM   = (int*)  alloc((size_t)1024 * 4);
    int*   CUR8   = (int*)  alloc((size_t)8 * 4);
    int*   CUR64  = (int*)  alloc((size_t)64 * 4);
    unsigned short* Wp1 = (unsigned short*)alloc((size_t)256 * 256 * 2);
    unsigned short* Wp2 = (unsigned short*)alloc((size_t)128 * 256 * 2);

    const int nb = (N + 1023) / 1024;   // 98

    // ---- degree + row_ptr ----
    hipMemsetAsync(DEG, 0, (size_t)N * 4, stream);
    deg_count<<<(E + 255) / 256, 256, 0, stream>>>(rows, DEG, E);
    inv_deg<<<(N + 255) / 256, 256, 0, stream>>>(DEG, INV, N);
    block_sums<<<nb, 1024, 0, stream>>>(DEG, BSUM, N);
    excl_scan<<<1, 1024, 0, stream>>>(BSUM, &ROWP[N], nb);
    scan_final<<<nb, 1024, 0, stream>>>(DEG, BSUM, ROWP, N);

    // ---- hierarchical binning -> CSR ----
    init_cursors<<<1, 64, 0, stream>>>(ROWP, CUR8, CUR64, N);
    bin_pass_a<<<(E + 255) / 256, 256, 0, stream>>>(rows, cols, CUR8, BIN8, E);
    bin_pass_b<<<(E + 255) / 256, 256, 0, stream>>>(BIN8, CUR64, BIN64, E);
    const int nwin = (N + 511) / 512;   // 196
    fill_csr_win<<<nwin, 256, 0, stream>>>(BIN64, ROWP, CSRC, N);

    // ---- dtype prep ----
    long long n4 = (long long)N * 256 / 4;
    conv_bf16<<<(int)((n4 + 255) / 256), 256, 0, stream>>>(x, Xb, n4);
    repack_W1p<<<256, 256, 0, stream>>>(W1, Wp1);
    repack_W2p<<<256, 128, 0, stream>>>(W2, Wp2);

    dim3 ggrid((N + 127) / 128, 2);
    const int gblocks = (int)(((long long)N * 64 + 255) / 256);

    // ---- layer 1 ----
    gemm_mfma<<<ggrid, 256, 0, stream>>>(Xb, Wp1, P, N, 256);
    gather_combine<<<gblocks, 256, 0, stream>>>(P, ROWP, CSRC, INV, H, N);

    // ---- layer 2 ----
    gemm_mfma<<<ggrid, 256, 0, stream>>>(H, Wp2, P, N, 128);
    gather_combine<<<gblocks, 256, 0, stream>>>(P, ROWP, CSRC, INV, H, N);

    // ---- head ----
    mlp_logsoftmax<<<(N + 3) / 4, 256, 0, stream>>>(H, mlpW, mlpb, (float*)d_out, N);
}

// Round 5
// 849.559 us; speedup vs baseline: 10.5445x; 10.5445x over previous
//
#include <hip/hip_runtime.h>
#include <hip/hip_bf16.h>

#define NFEAT 256
#define NHID  128
#define NCLASS 40

typedef __attribute__((ext_vector_type(8))) short short8;
typedef __attribute__((ext_vector_type(4))) float float4v;

__device__ __forceinline__ unsigned short f2bf(float f) {
    union { float f; unsigned u; } v; v.f = f;
    unsigned r = v.u + 0x7fff + ((v.u >> 16) & 1);   // RNE
    return (unsigned short)(r >> 16);
}
__device__ __forceinline__ float bflo(unsigned u) { return __uint_as_float(u << 16); }
__device__ __forceinline__ float bfhi(unsigned u) { return __uint_as_float(u & 0xffff0000u); }
__device__ __forceinline__ unsigned packbf(float a, float b) {
    return (unsigned)f2bf(a) | ((unsigned)f2bf(b) << 16);
}

#define TILE_E 8192   // edges per binning block

// ---- K1: per-block LDS histogram of row>>9 buckets -> few global atomics ----
__global__ __launch_bounds__(256) void bin_hist(const int* __restrict__ rows,
                                                int* __restrict__ ghist, int E, int nbuck) {
    __shared__ int hh[256];
    int t = threadIdx.x;
    hh[t] = 0;
    __syncthreads();
    int e0 = blockIdx.x * TILE_E;
    #pragma unroll 4
    for (int it = 0; it < TILE_E / 256; ++it) {
        int e = e0 + it * 256 + t;
        if (e < E) atomicAdd(&hh[rows[e] >> 9], 1);
    }
    __syncthreads();
    if (t < nbuck && hh[t]) atomicAdd(&ghist[t], hh[t]);
}

// ---- K2: scan bucket counts -> bases + cursors; row_ptr[N] = E ----
__global__ void scan_buckets(const int* __restrict__ ghist, int* __restrict__ gbase,
                             int* __restrict__ gcur, int* __restrict__ row_ptr,
                             int nbuck, int N, int E) {
    __shared__ int s[256];
    int t = threadIdx.x;
    int v = (t < nbuck) ? ghist[t] : 0;
    s[t] = v;
    __syncthreads();
    for (int off = 1; off < 256; off <<= 1) {
        int tmp = (t >= off) ? s[t - off] : 0;
        __syncthreads();
        s[t] += tmp;
        __syncthreads();
    }
    int excl = s[t] - v;
    if (t < nbuck) { gbase[t] = excl; gcur[t] = excl; }
    if (t == 0) { gbase[nbuck] = E; row_ptr[N] = E; }
}

// ---- K3: re-histogram tile, reserve per-bucket chunks, scatter pairs ----
__global__ __launch_bounds__(256) void bin_scatter(const int* __restrict__ rows,
                                                   const int* __restrict__ cols,
                                                   int* __restrict__ gcur,
                                                   int2* __restrict__ binned, int E, int nbuck) {
    __shared__ int hh[256];
    __shared__ int lbase[256];
    __shared__ int lcur[256];
    int t = threadIdx.x;
    hh[t] = 0;
    __syncthreads();
    int e0 = blockIdx.x * TILE_E;
    #pragma unroll 4
    for (int it = 0; it < TILE_E / 256; ++it) {
        int e = e0 + it * 256 + t;
        if (e < E) atomicAdd(&hh[rows[e] >> 9], 1);
    }
    __syncthreads();
    if (t < nbuck) {
        lbase[t] = hh[t] ? atomicAdd(&gcur[t], hh[t]) : 0;
        lcur[t] = 0;
    }
    __syncthreads();
    #pragma unroll 4
    for (int it = 0; it < TILE_E / 256; ++it) {
        int e = e0 + it * 256 + t;
        if (e < E) {
            int r = rows[e];
            int b = r >> 9;
            int dst = lbase[b] + atomicAdd(&lcur[b], 1);
            binned[dst] = make_int2(r, cols[e]);
        }
    }
}

// ---- K4: one block per 512-row window: degrees+scan -> row_ptr, inv_deg, CSR cols ----
__global__ __launch_bounds__(256) void fill_win(const int2* __restrict__ binned,
                                                const int* __restrict__ gbase,
                                                int* __restrict__ row_ptr,
                                                float* __restrict__ inv,
                                                int* __restrict__ csr_cols, int N) {
    __shared__ int h[512];
    __shared__ int ps[256];
    __shared__ int lcur[512];
    int t = threadIdx.x;
    int w = blockIdx.x;
    int r0 = w << 9;
    h[t] = 0; h[t + 256] = 0;
    __syncthreads();
    int beg = gbase[w], end = gbase[w + 1];
    for (int e = beg + t; e < end; e += 256)
        atomicAdd(&h[binned[e].x & 511], 1);
    __syncthreads();
    int pair = h[2 * t] + h[2 * t + 1];
    ps[t] = pair;
    __syncthreads();
    for (int off = 1; off < 256; off <<= 1) {
        int tmp = (t >= off) ? ps[t - off] : 0;
        __syncthreads();
        ps[t] += tmp;
        __syncthreads();
    }
    int base0 = beg + ps[t] - pair;
    int base1 = base0 + h[2 * t];
    int r_a = r0 + 2 * t, r_b = r0 + 2 * t + 1;
    if (r_a < N) { row_ptr[r_a] = base0; inv[r_a] = 1.0f / ((float)h[2 * t] + 1.0f); }
    if (r_b < N) { row_ptr[r_b] = base1; inv[r_b] = 1.0f / ((float)h[2 * t + 1] + 1.0f); }
    lcur[2 * t] = base0;
    lcur[2 * t + 1] = base1;
    __syncthreads();
    for (int e = beg + t; e < end; e += 256) {
        int2 rc = binned[e];
        int idx = atomicAdd(&lcur[rc.x & 511], 1);
        csr_cols[idx] = rc.y;
    }
}

// ---------------- fp32 -> bf16 conversion of x ----------------
__global__ void conv_bf16(const float* __restrict__ in, unsigned short* __restrict__ out, long long n4) {
    long long i = (long long)blockIdx.x * blockDim.x + threadIdx.x;
    if (i >= n4) return;
    float4 v = *reinterpret_cast<const float4*>(&in[i * 4]);
    ushort4 o;
    o.x = f2bf(v.x); o.y = f2bf(v.y); o.z = f2bf(v.z); o.w = f2bf(v.w);
    *reinterpret_cast<ushort4*>(&out[i * 4]) = o;
}

// ---------------- weight repack to bf16 K-panel layout: Wp[k0/32][o(256)][k(32)] ----------------
__global__ void repack_W1p(const float* __restrict__ W1, unsigned short* __restrict__ Wp) {
    int o = blockIdx.x;       // 0..255
    int k = threadIdx.x;      // 0..255
    float v = (o < 128) ? W1[o * 512 + k] : W1[(o - 128) * 512 + 256 + k];
    Wp[(size_t)(k >> 5) * 256 * 32 + o * 32 + (k & 31)] = f2bf(v);
}

__global__ void repack_W2p(const float* __restrict__ W2, unsigned short* __restrict__ Wp) {
    int o = blockIdx.x;       // 0..255
    int k = threadIdx.x;      // 0..127
    float v = (o < 128) ? W2[o * 256 + k] : W2[(o - 128) * 256 + 128 + k];
    Wp[(size_t)(k >> 5) * 256 * 32 + o * 32 + (k & 31)] = f2bf(v);
}

// ---------------- bf16 MFMA GEMM: P[M x 256] = Xb[M x K] @ W (packed) ----------------
#define LDK 40
__global__ __launch_bounds__(256) void gemm_mfma(const unsigned short* __restrict__ Xb,
                                                 const unsigned short* __restrict__ Wp,
                                                 unsigned short* __restrict__ P,
                                                 int M, int K) {
    __shared__ unsigned short sA[128][LDK];
    __shared__ unsigned short sB[128][LDK];
    const int t    = threadIdx.x;
    const int lane = t & 63;
    const int wave = t >> 6;
    const int m0 = blockIdx.x * 128;
    const int n0 = blockIdx.y * 128;
    const int wm = (wave >> 1) * 64;
    const int wn = (wave & 1) * 64;

    const int lrow = t >> 2;
    const int lk   = (t & 3) * 8;
    const int r15  = lane & 15;
    const int k8   = (lane >> 4) * 8;

    float4v acc[4][4] = {{{0.f,0.f,0.f,0.f}}};

    for (int k0 = 0; k0 < K; k0 += 32) {
        #pragma unroll
        for (int it = 0; it < 2; ++it) {
            int r  = lrow + it * 64;
            int gm = m0 + r;
            float4 v = make_float4(0.f, 0.f, 0.f, 0.f);
            if (gm < M) v = *reinterpret_cast<const float4*>(&Xb[(size_t)gm * K + k0 + lk]);
            *reinterpret_cast<float4*>(&sA[r][lk]) = v;
        }
        const unsigned short* pan = Wp + ((size_t)(k0 >> 5) * 256 + n0) * 32;
        #pragma unroll
        for (int it = 0; it < 2; ++it) {
            int r = lrow + it * 64;
            float4 v = *reinterpret_cast<const float4*>(&pan[(size_t)r * 32 + lk]);
            *reinterpret_cast<float4*>(&sB[r][lk]) = v;
        }
        __syncthreads();

        short8 aF[4], bF[4];
        #pragma unroll
        for (int i = 0; i < 4; ++i)
            aF[i] = *reinterpret_cast<const short8*>(&sA[wm + i * 16 + r15][k8]);
        #pragma unroll
        for (int j = 0; j < 4; ++j)
            bF[j] = *reinterpret_cast<const short8*>(&sB[wn + j * 16 + r15][k8]);
        #pragma unroll
        for (int i = 0; i < 4; ++i)
            #pragma unroll
            for (int j = 0; j < 4; ++j)
                acc[i][j] = __builtin_amdgcn_mfma_f32_16x16x32_bf16(aF[i], bF[j], acc[i][j], 0, 0, 0);
        __syncthreads();
    }

    #pragma unroll
    for (int i = 0; i < 4; ++i) {
        #pragma unroll
        for (int r = 0; r < 4; ++r) {
            int row = m0 + wm + i * 16 + (lane >> 4) * 4 + r;
            if (row < M) {
                #pragma unroll
                for (int j = 0; j < 4; ++j)
                    P[(size_t)row * 256 + n0 + wn + j * 16 + r15] = f2bf(acc[i][j][r]);
            }
        }
    }
}

// ---------------- gather-aggregate + combine + relu: one wave per node ----------------
__global__ __launch_bounds__(256) void gather_combine(const unsigned short* __restrict__ P,
                                                      const int* __restrict__ row_ptr,
                                                      const int* __restrict__ csr_cols,
                                                      const float* __restrict__ invdeg,
                                                      unsigned short* __restrict__ H, int N) {
    int node = (blockIdx.x * blockDim.x + threadIdx.x) >> 6;
    if (node >= N) return;
    int lane = threadIdx.x & 63;
    int grp  = lane >> 4;
    int l16  = lane & 15;
    int beg = row_ptr[node], end = row_ptr[node + 1];

    float a0=0,a1=0,a2=0,a3=0,a4=0,a5=0,a6=0,a7=0;
    for (int p = beg + grp; p < end; p += 4) {
        int c = csr_cols[p];
        uint4 u = *reinterpret_cast<const uint4*>(&P[(size_t)c * 256 + 128 + l16 * 8]);
        a0 += bflo(u.x); a1 += bfhi(u.x);
        a2 += bflo(u.y); a3 += bfhi(u.y);
        a4 += bflo(u.z); a5 += bfhi(u.z);
        a6 += bflo(u.w); a7 += bfhi(u.w);
    }
    a0 += __shfl_xor(a0, 16); a1 += __shfl_xor(a1, 16);
    a2 += __shfl_xor(a2, 16); a3 += __shfl_xor(a3, 16);
    a4 += __shfl_xor(a4, 16); a5 += __shfl_xor(a5, 16);
    a6 += __shfl_xor(a6, 16); a7 += __shfl_xor(a7, 16);
    a0 += __shfl_xor(a0, 32); a1 += __shfl_xor(a1, 32);
    a2 += __shfl_xor(a2, 32); a3 += __shfl_xor(a3, 32);
    a4 += __shfl_xor(a4, 32); a5 += __shfl_xor(a5, 32);
    a6 += __shfl_xor(a6, 32); a7 += __shfl_xor(a7, 32);

    if (grp == 0) {
        float id = invdeg[node];
        uint4 us = *reinterpret_cast<const uint4*>(&P[(size_t)node * 256 + l16 * 8]);
        float h0 = fmaxf(fmaf(a0, id, bflo(us.x)), 0.f);
        float h1 = fmaxf(fmaf(a1, id, bfhi(us.x)), 0.f);
        float h2 = fmaxf(fmaf(a2, id, bflo(us.y)), 0.f);
        float h3 = fmaxf(fmaf(a3, id, bfhi(us.y)), 0.f);
        float h4 = fmaxf(fmaf(a4, id, bflo(us.z)), 0.f);
        float h5 = fmaxf(fmaf(a5, id, bfhi(us.z)), 0.f);
        float h6 = fmaxf(fmaf(a6, id, bflo(us.w)), 0.f);
        float h7 = fmaxf(fmaf(a7, id, bfhi(us.w)), 0.f);
        uint4 o;
        o.x = packbf(h0, h1); o.y = packbf(h2, h3);
        o.z = packbf(h4, h5); o.w = packbf(h6, h7);
        *reinterpret_cast<uint4*>(&H[(size_t)node * 128 + l16 * 8]) = o;
    }
}

// ---------------- MLP head + log_softmax: one wave per node ----------------
__global__ __launch_bounds__(256) void mlp_logsoftmax(const unsigned short* __restrict__ H,
                                                      const float* __restrict__ Wm,
                                                      const float* __restrict__ bm,
                                                      float* __restrict__ out, int N) {
    __shared__ float sh[4][128];
    const int w    = threadIdx.x >> 6;
    const int lane = threadIdx.x & 63;
    const int n    = blockIdx.x * 4 + w;
    if (n < N) {
        unsigned u = *reinterpret_cast<const unsigned*>(&H[(size_t)n * 128 + lane * 2]);
        sh[w][lane * 2 + 0] = bflo(u);
        sh[w][lane * 2 + 1] = bfhi(u);
    }
    __syncthreads();
    if (n >= N) return;

    float logit = -1e30f;
    if (lane < NCLASS) {
        float acc = bm[lane];
        const float* wrow = &Wm[lane * 128];
        #pragma unroll 8
        for (int k = 0; k < 128; ++k) acc += sh[w][k] * wrow[k];
        logit = acc;
    }
    float m = logit;
    #pragma unroll
    for (int off = 32; off; off >>= 1) m = fmaxf(m, __shfl_xor(m, off));
    float e = (lane < NCLASS) ? __expf(logit - m) : 0.f;
    float s = e;
    #pragma unroll
    for (int off = 32; off; off >>= 1) s += __shfl_xor(s, off);
    if (lane < NCLASS) out[(size_t)n * NCLASS + lane] = logit - m - __logf(s);
}

extern "C" void kernel_launch(void* const* d_in, const int* in_sizes, int n_in,
                              void* d_out, int out_size, void* d_ws, size_t ws_size,
                              hipStream_t stream) {
    const float* x    = (const float*)d_in[0];
    const float* W1   = (const float*)d_in[1];
    const float* W2   = (const float*)d_in[2];
    const float* mlpW = (const float*)d_in[3];
    const float* mlpb = (const float*)d_in[4];
    const int*   rows = (const int*)d_in[5];
    const int*   cols = (const int*)d_in[6];

    const int N = in_sizes[0] / NFEAT;   // 100000
    const int E = in_sizes[5];           // 3200000

    char* ws = (char*)d_ws;
    size_t off = 0;
    auto alloc = [&](size_t bytes) -> void* {
        void* p = ws + off;
        off = (off + bytes + 255) & ~(size_t)255;
        return p;
    };
    unsigned short* Xb  = (unsigned short*)alloc((size_t)N * 256 * 2);
    unsigned short* P   = (unsigned short*)alloc((size_t)N * 256 * 2);
    unsigned short* H   = (unsigned short*)alloc((size_t)N * 128 * 2);
    float* INV    = (float*)alloc((size_t)N * 4);
    int*   ROWP   = (int*)  alloc((size_t)(N + 1) * 4);
    int*   CSRC   = (int*)  alloc((size_t)E * 4);
    int2*  BINNED = (int2*) alloc((size_t)E * 8);
    int*   GHIST  = (int*)  alloc((size_t)256 * 4);
    int*   GBASE  = (int*)  alloc((size_t)257 * 4);
    int*   GCUR   = (int*)  alloc((size_t)256 * 4);
    unsigned short* Wp1 = (unsigned short*)alloc((size_t)256 * 256 * 2);
    unsigned short* Wp2 = (unsigned short*)alloc((size_t)128 * 256 * 2);

    const int nbuck = (N + 511) >> 9;              // 196
    const int nblk  = (E + TILE_E - 1) / TILE_E;   // 391

    // ---- CSR build via LDS-histogram binning (also produces row_ptr + inv_deg) ----
    hipMemsetAsync(GHIST, 0, 256 * 4, stream);
    bin_hist<<<nblk, 256, 0, stream>>>(rows, GHIST, E, nbuck);
    scan_buckets<<<1, 256, 0, stream>>>(GHIST, GBASE, GCUR, ROWP, nbuck, N, E);
    bin_scatter<<<nblk, 256, 0, stream>>>(rows, cols, GCUR, BINNED, E, nbuck);
    fill_win<<<nbuck, 256, 0, stream>>>(BINNED, GBASE, ROWP, INV, CSRC, N);

    // ---- dtype prep ----
    long long n4 = (long long)N * 256 / 4;
    conv_bf16<<<(int)((n4 + 255) / 256), 256, 0, stream>>>(x, Xb, n4);
    repack_W1p<<<256, 256, 0, stream>>>(W1, Wp1);
    repack_W2p<<<256, 128, 0, stream>>>(W2, Wp2);

    dim3 ggrid((N + 127) / 128, 2);
    const int gblocks = (int)(((long long)N * 64 + 255) / 256);

    // ---- layer 1 ----
    gemm_mfma<<<ggrid, 256, 0, stream>>>(Xb, Wp1, P, N, 256);
    gather_combine<<<gblocks, 256, 0, stream>>>(P, ROWP, CSRC, INV, H, N);

    // ---- layer 2 ----
    gemm_mfma<<<ggrid, 256, 0, stream>>>(H, Wp2, P, N, 128);
    gather_combine<<<gblocks, 256, 0, stream>>>(P, ROWP, CSRC, INV, H, N);

    // ---- head ----
    mlp_logsoftmax<<<(N + 3) / 4, 256, 0, stream>>>(H, mlpW, mlpb, (float*)d_out, N);
}

// Round 6
// 616.905 us; speedup vs baseline: 14.5212x; 1.3771x over previous
//
#include <hip/hip_runtime.h>
#include <hip/hip_bf16.h>

#define NFEAT 256
#define NHID  128
#define NCLASS 40

typedef __attribute__((ext_vector_type(8))) short short8;
typedef __attribute__((ext_vector_type(4))) float float4v;

__device__ __forceinline__ unsigned short f2bf(float f) {
    union { float f; unsigned u; } v; v.f = f;
    unsigned r = v.u + 0x7fff + ((v.u >> 16) & 1);   // RNE
    return (unsigned short)(r >> 16);
}
__device__ __forceinline__ float bflo(unsigned u) { return __uint_as_float(u << 16); }
__device__ __forceinline__ float bfhi(unsigned u) { return __uint_as_float(u & 0xffff0000u); }
__device__ __forceinline__ unsigned packbf(float a, float b) {
    return (unsigned)f2bf(a) | ((unsigned)f2bf(b) << 16);
}

#define TILE_E 8192   // edges per binning block

// ---- K1: per-block LDS histogram of row>>9 buckets -> few global atomics ----
__global__ __launch_bounds__(256) void bin_hist(const int* __restrict__ rows,
                                                int* __restrict__ ghist, int E, int nbuck) {
    __shared__ int hh[256];
    int t = threadIdx.x;
    hh[t] = 0;
    __syncthreads();
    int e0 = blockIdx.x * TILE_E;
    #pragma unroll 4
    for (int it = 0; it < TILE_E / 256; ++it) {
        int e = e0 + it * 256 + t;
        if (e < E) atomicAdd(&hh[rows[e] >> 9], 1);
    }
    __syncthreads();
    if (t < nbuck && hh[t]) atomicAdd(&ghist[t], hh[t]);
}

// ---- K2: scan bucket counts -> bases + cursors; row_ptr[N] = E ----
__global__ void scan_buckets(const int* __restrict__ ghist, int* __restrict__ gbase,
                             int* __restrict__ gcur, int* __restrict__ row_ptr,
                             int nbuck, int N, int E) {
    __shared__ int s[256];
    int t = threadIdx.x;
    int v = (t < nbuck) ? ghist[t] : 0;
    s[t] = v;
    __syncthreads();
    for (int off = 1; off < 256; off <<= 1) {
        int tmp = (t >= off) ? s[t - off] : 0;
        __syncthreads();
        s[t] += tmp;
        __syncthreads();
    }
    int excl = s[t] - v;
    if (t < nbuck) { gbase[t] = excl; gcur[t] = excl; }
    if (t == 0) { gbase[nbuck] = E; row_ptr[N] = E; }
}

// ---- K3: re-histogram tile, reserve per-bucket chunks, scatter pairs ----
__global__ __launch_bounds__(256) void bin_scatter(const int* __restrict__ rows,
                                                   const int* __restrict__ cols,
                                                   int* __restrict__ gcur,
                                                   int2* __restrict__ binned, int E, int nbuck) {
    __shared__ int hh[256];
    __shared__ int lbase[256];
    __shared__ int lcur[256];
    int t = threadIdx.x;
    hh[t] = 0;
    __syncthreads();
    int e0 = blockIdx.x * TILE_E;
    #pragma unroll 4
    for (int it = 0; it < TILE_E / 256; ++it) {
        int e = e0 + it * 256 + t;
        if (e < E) atomicAdd(&hh[rows[e] >> 9], 1);
    }
    __syncthreads();
    if (t < nbuck) {
        lbase[t] = hh[t] ? atomicAdd(&gcur[t], hh[t]) : 0;
        lcur[t] = 0;
    }
    __syncthreads();
    #pragma unroll 4
    for (int it = 0; it < TILE_E / 256; ++it) {
        int e = e0 + it * 256 + t;
        if (e < E) {
            int r = rows[e];
            int b = r >> 9;
            int dst = lbase[b] + atomicAdd(&lcur[b], 1);
            binned[dst] = make_int2(r, cols[e]);
        }
    }
}

// ---- K4: one block per 512-row window: degrees+scan -> row_ptr, inv_deg, CSR cols ----
__global__ __launch_bounds__(256) void fill_win(const int2* __restrict__ binned,
                                                const int* __restrict__ gbase,
                                                int* __restrict__ row_ptr,
                                                float* __restrict__ inv,
                                                int* __restrict__ csr_cols, int N) {
    __shared__ int h[512];
    __shared__ int ps[256];
    __shared__ int lcur[512];
    int t = threadIdx.x;
    int w = blockIdx.x;
    int r0 = w << 9;
    h[t] = 0; h[t + 256] = 0;
    __syncthreads();
    int beg = gbase[w], end = gbase[w + 1];
    for (int e = beg + t; e < end; e += 256)
        atomicAdd(&h[binned[e].x & 511], 1);
    __syncthreads();
    int pair = h[2 * t] + h[2 * t + 1];
    ps[t] = pair;
    __syncthreads();
    for (int off = 1; off < 256; off <<= 1) {
        int tmp = (t >= off) ? ps[t - off] : 0;
        __syncthreads();
        ps[t] += tmp;
        __syncthreads();
    }
    int base0 = beg + ps[t] - pair;
    int base1 = base0 + h[2 * t];
    int r_a = r0 + 2 * t, r_b = r0 + 2 * t + 1;
    if (r_a < N) { row_ptr[r_a] = base0; inv[r_a] = 1.0f / ((float)h[2 * t] + 1.0f); }
    if (r_b < N) { row_ptr[r_b] = base1; inv[r_b] = 1.0f / ((float)h[2 * t + 1] + 1.0f); }
    lcur[2 * t] = base0;
    lcur[2 * t + 1] = base1;
    __syncthreads();
    for (int e = beg + t; e < end; e += 256) {
        int2 rc = binned[e];
        int idx = atomicAdd(&lcur[rc.x & 511], 1);
        csr_cols[idx] = rc.y;
    }
}

// ---------------- fp32 -> bf16 conversion of x ----------------
__global__ void conv_bf16(const float* __restrict__ in, unsigned short* __restrict__ out, long long n4) {
    long long i = (long long)blockIdx.x * blockDim.x + threadIdx.x;
    if (i >= n4) return;
    float4 v = *reinterpret_cast<const float4*>(&in[i * 4]);
    ushort4 o;
    o.x = f2bf(v.x); o.y = f2bf(v.y); o.z = f2bf(v.z); o.w = f2bf(v.w);
    *reinterpret_cast<ushort4*>(&out[i * 4]) = o;
}

// ---------------- weight repack to bf16 K-panel layout: Wp[k0/32][o(256)][k(32)] ----------------
__global__ void repack_W1p(const float* __restrict__ W1, unsigned short* __restrict__ Wp) {
    int o = blockIdx.x;       // 0..255
    int k = threadIdx.x;      // 0..255
    float v = (o < 128) ? W1[o * 512 + k] : W1[(o - 128) * 512 + 256 + k];
    Wp[(size_t)(k >> 5) * 256 * 32 + o * 32 + (k & 31)] = f2bf(v);
}

__global__ void repack_W2p(const float* __restrict__ W2, unsigned short* __restrict__ Wp) {
    int o = blockIdx.x;       // 0..255
    int k = threadIdx.x;      // 0..127
    float v = (o < 128) ? W2[o * 256 + k] : W2[(o - 128) * 256 + 128 + k];
    Wp[(size_t)(k >> 5) * 256 * 32 + o * 32 + (k & 31)] = f2bf(v);
}

// ---------------- head weight repack: Wb[48][128] bf16, zero-padded classes ----------------
__global__ void repack_Wm(const float* __restrict__ Wm, unsigned short* __restrict__ Wb) {
    int o = blockIdx.x;       // 0..47
    int k = threadIdx.x;      // 0..127
    Wb[o * 128 + k] = (o < NCLASS) ? f2bf(Wm[o * 128 + k]) : 0;
}

// ---------------- bf16 MFMA GEMM: P[M x 256] = Xb[M x K] @ W (packed) ----------------
#define LDK 40
__global__ __launch_bounds__(256) void gemm_mfma(const unsigned short* __restrict__ Xb,
                                                 const unsigned short* __restrict__ Wp,
                                                 unsigned short* __restrict__ P,
                                                 int M, int K) {
    __shared__ unsigned short sA[128][LDK];
    __shared__ unsigned short sB[128][LDK];
    const int t    = threadIdx.x;
    const int lane = t & 63;
    const int wave = t >> 6;
    const int m0 = blockIdx.x * 128;
    const int n0 = blockIdx.y * 128;
    const int wm = (wave >> 1) * 64;
    const int wn = (wave & 1) * 64;

    const int lrow = t >> 2;
    const int lk   = (t & 3) * 8;
    const int r15  = lane & 15;
    const int k8   = (lane >> 4) * 8;

    float4v acc[4][4] = {{{0.f,0.f,0.f,0.f}}};

    for (int k0 = 0; k0 < K; k0 += 32) {
        #pragma unroll
        for (int it = 0; it < 2; ++it) {
            int r  = lrow + it * 64;
            int gm = m0 + r;
            float4 v = make_float4(0.f, 0.f, 0.f, 0.f);
            if (gm < M) v = *reinterpret_cast<const float4*>(&Xb[(size_t)gm * K + k0 + lk]);
            *reinterpret_cast<float4*>(&sA[r][lk]) = v;
        }
        const unsigned short* pan = Wp + ((size_t)(k0 >> 5) * 256 + n0) * 32;
        #pragma unroll
        for (int it = 0; it < 2; ++it) {
            int r = lrow + it * 64;
            float4 v = *reinterpret_cast<const float4*>(&pan[(size_t)r * 32 + lk]);
            *reinterpret_cast<float4*>(&sB[r][lk]) = v;
        }
        __syncthreads();

        short8 aF[4], bF[4];
        #pragma unroll
        for (int i = 0; i < 4; ++i)
            aF[i] = *reinterpret_cast<const short8*>(&sA[wm + i * 16 + r15][k8]);
        #pragma unroll
        for (int j = 0; j < 4; ++j)
            bF[j] = *reinterpret_cast<const short8*>(&sB[wn + j * 16 + r15][k8]);
        #pragma unroll
        for (int i = 0; i < 4; ++i)
            #pragma unroll
            for (int j = 0; j < 4; ++j)
                acc[i][j] = __builtin_amdgcn_mfma_f32_16x16x32_bf16(aF[i], bF[j], acc[i][j], 0, 0, 0);
        __syncthreads();
    }

    #pragma unroll
    for (int i = 0; i < 4; ++i) {
        #pragma unroll
        for (int r = 0; r < 4; ++r) {
            int row = m0 + wm + i * 16 + (lane >> 4) * 4 + r;
            if (row < M) {
                #pragma unroll
                for (int j = 0; j < 4; ++j)
                    P[(size_t)row * 256 + n0 + wn + j * 16 + r15] = f2bf(acc[i][j][r]);
            }
        }
    }
}

// ---------------- gather-aggregate + combine + relu: one wave per node ----------------
__global__ __launch_bounds__(256) void gather_combine(const unsigned short* __restrict__ P,
                                                      const int* __restrict__ row_ptr,
                                                      const int* __restrict__ csr_cols,
                                                      const float* __restrict__ invdeg,
                                                      unsigned short* __restrict__ H, int N) {
    int node = (blockIdx.x * blockDim.x + threadIdx.x) >> 6;
    if (node >= N) return;
    int lane = threadIdx.x & 63;
    int grp  = lane >> 4;
    int l16  = lane & 15;
    int beg = row_ptr[node], end = row_ptr[node + 1];

    float a0=0,a1=0,a2=0,a3=0,a4=0,a5=0,a6=0,a7=0;
    for (int p = beg + grp; p < end; p += 4) {
        int c = csr_cols[p];
        uint4 u = *reinterpret_cast<const uint4*>(&P[(size_t)c * 256 + 128 + l16 * 8]);
        a0 += bflo(u.x); a1 += bfhi(u.x);
        a2 += bflo(u.y); a3 += bfhi(u.y);
        a4 += bflo(u.z); a5 += bfhi(u.z);
        a6 += bflo(u.w); a7 += bfhi(u.w);
    }
    a0 += __shfl_xor(a0, 16); a1 += __shfl_xor(a1, 16);
    a2 += __shfl_xor(a2, 16); a3 += __shfl_xor(a3, 16);
    a4 += __shfl_xor(a4, 16); a5 += __shfl_xor(a5, 16);
    a6 += __shfl_xor(a6, 16); a7 += __shfl_xor(a7, 16);
    a0 += __shfl_xor(a0, 32); a1 += __shfl_xor(a1, 32);
    a2 += __shfl_xor(a2, 32); a3 += __shfl_xor(a3, 32);
    a4 += __shfl_xor(a4, 32); a5 += __shfl_xor(a5, 32);
    a6 += __shfl_xor(a6, 32); a7 += __shfl_xor(a7, 32);

    if (grp == 0) {
        float id = invdeg[node];
        uint4 us = *reinterpret_cast<const uint4*>(&P[(size_t)node * 256 + l16 * 8]);
        float h0 = fmaxf(fmaf(a0, id, bflo(us.x)), 0.f);
        float h1 = fmaxf(fmaf(a1, id, bfhi(us.x)), 0.f);
        float h2 = fmaxf(fmaf(a2, id, bflo(us.y)), 0.f);
        float h3 = fmaxf(fmaf(a3, id, bfhi(us.y)), 0.f);
        float h4 = fmaxf(fmaf(a4, id, bflo(us.z)), 0.f);
        float h5 = fmaxf(fmaf(a5, id, bfhi(us.z)), 0.f);
        float h6 = fmaxf(fmaf(a6, id, bflo(us.w)), 0.f);
        float h7 = fmaxf(fmaf(a7, id, bfhi(us.w)), 0.f);
        uint4 o;
        o.x = packbf(h0, h1); o.y = packbf(h2, h3);
        o.z = packbf(h4, h5); o.w = packbf(h6, h7);
        *reinterpret_cast<uint4*>(&H[(size_t)node * 128 + l16 * 8]) = o;
    }
}

// ---------------- MFMA head: logits = H @ Wb^T (+bias), fused log_softmax ----------------
// Block = 4 waves x 16 nodes = 64 nodes. 3 class-tiles of 16 (40 padded to 48).
__global__ __launch_bounds__(256) void mlp_head_mfma(const unsigned short* __restrict__ H,
                                                     const unsigned short* __restrict__ Wb,
                                                     const float* __restrict__ bm,
                                                     float* __restrict__ out, int N) {
    __shared__ unsigned short sW[48 * 128];   // 12 KB
    int t = threadIdx.x;
    for (int i = t; i < 48 * 128 / 2; i += 256)
        ((unsigned*)sW)[i] = ((const unsigned*)Wb)[i];
    __syncthreads();

    const int wave = t >> 6, lane = t & 63;
    const int m0 = blockIdx.x * 64 + wave * 16;
    if (m0 >= N) return;
    const int r15 = lane & 15;
    const int k8  = (lane >> 4) * 8;
    const int arow = min(m0 + r15, N - 1);

    float4v acc[3] = {{0.f,0.f,0.f,0.f},{0.f,0.f,0.f,0.f},{0.f,0.f,0.f,0.f}};
    #pragma unroll
    for (int k0 = 0; k0 < 128; k0 += 32) {
        short8 a = *reinterpret_cast<const short8*>(&H[(size_t)arow * 128 + k0 + k8]);
        #pragma unroll
        for (int f = 0; f < 3; ++f) {
            short8 b = *reinterpret_cast<const short8*>(&sW[(f * 16 + r15) * 128 + k0 + k8]);
            acc[f] = __builtin_amdgcn_mfma_f32_16x16x32_bf16(a, b, acc[f], 0, 0, 0);
        }
    }

    // C layout: node row = (lane>>4)*4 + reg, class col = f*16 + (lane&15)
    float bias[3]; bool cv[3];
    #pragma unroll
    for (int f = 0; f < 3; ++f) {
        int c = f * 16 + r15;
        cv[f] = (c < NCLASS);
        bias[f] = cv[f] ? bm[c] : 0.f;
    }
    #pragma unroll
    for (int r = 0; r < 4; ++r) {
        int node = m0 + (lane >> 4) * 4 + r;
        float lg[3];
        float m = -1e30f;
        #pragma unroll
        for (int f = 0; f < 3; ++f) {
            lg[f] = cv[f] ? (acc[f][r] + bias[f]) : -1e30f;
            m = fmaxf(m, lg[f]);
        }
        m = fmaxf(m, __shfl_xor(m, 1));
        m = fmaxf(m, __shfl_xor(m, 2));
        m = fmaxf(m, __shfl_xor(m, 4));
        m = fmaxf(m, __shfl_xor(m, 8));
        float s = 0.f;
        #pragma unroll
        for (int f = 0; f < 3; ++f) s += cv[f] ? __expf(lg[f] - m) : 0.f;
        s += __shfl_xor(s, 1);
        s += __shfl_xor(s, 2);
        s += __shfl_xor(s, 4);
        s += __shfl_xor(s, 8);
        float ls = __logf(s);
        if (node < N) {
            #pragma unroll
            for (int f = 0; f < 3; ++f)
                if (cv[f]) out[(size_t)node * NCLASS + f * 16 + r15] = lg[f] - m - ls;
        }
    }
}

extern "C" void kernel_launch(void* const* d_in, const int* in_sizes, int n_in,
                              void* d_out, int out_size, void* d_ws, size_t ws_size,
                              hipStream_t stream) {
    const float* x    = (const float*)d_in[0];
    const float* W1   = (const float*)d_in[1];
    const float* W2   = (const float*)d_in[2];
    const float* mlpW = (const float*)d_in[3];
    const float* mlpb = (const float*)d_in[4];
    const int*   rows = (const int*)d_in[5];
    const int*   cols = (const int*)d_in[6];

    const int N = in_sizes[0] / NFEAT;   // 100000
    const int E = in_sizes[5];           // 3200000

    char* ws = (char*)d_ws;
    size_t off = 0;
    auto alloc = [&](size_t bytes) -> void* {
        void* p = ws + off;
        off = (off + bytes + 255) & ~(size_t)255;
        return p;
    };
    unsigned short* Xb  = (unsigned short*)alloc((size_t)N * 256 * 2);
    unsigned short* P   = (unsigned short*)alloc((size_t)N * 256 * 2);
    unsigned short* H   = (unsigned short*)alloc((size_t)N * 128 * 2);
    float* INV    = (float*)alloc((size_t)N * 4);
    int*   ROWP   = (int*)  alloc((size_t)(N + 1) * 4);
    int*   CSRC   = (int*)  alloc((size_t)E * 4);
    int2*  BINNED = (int2*) alloc((size_t)E * 8);
    int*   GHIST  = (int*)  alloc((size_t)256 * 4);
    int*   GBASE  = (int*)  alloc((size_t)257 * 4);
    int*   GCUR   = (int*)  alloc((size_t)256 * 4);
    unsigned short* Wp1 = (unsigned short*)alloc((size_t)256 * 256 * 2);
    unsigned short* Wp2 = (unsigned short*)alloc((size_t)128 * 256 * 2);
    unsigned short* Wb  = (unsigned short*)alloc((size_t)48 * 128 * 2);

    const int nbuck = (N + 511) >> 9;              // 196
    const int nblk  = (E + TILE_E - 1) / TILE_E;   // 391

    // ---- CSR build via LDS-histogram binning (also produces row_ptr + inv_deg) ----
    hipMemsetAsync(GHIST, 0, 256 * 4, stream);
    bin_hist<<<nblk, 256, 0, stream>>>(rows, GHIST, E, nbuck);
    scan_buckets<<<1, 256, 0, stream>>>(GHIST, GBASE, GCUR, ROWP, nbuck, N, E);
    bin_scatter<<<nblk, 256, 0, stream>>>(rows, cols, GCUR, BINNED, E, nbuck);
    fill_win<<<nbuck, 256, 0, stream>>>(BINNED, GBASE, ROWP, INV, CSRC, N);

    // ---- dtype prep ----
    long long n4 = (long long)N * 256 / 4;
    conv_bf16<<<(int)((n4 + 255) / 256), 256, 0, stream>>>(x, Xb, n4);
    repack_W1p<<<256, 256, 0, stream>>>(W1, Wp1);
    repack_W2p<<<256, 128, 0, stream>>>(W2, Wp2);
    repack_Wm<<<48, 128, 0, stream>>>(mlpW, Wb);

    dim3 ggrid((N + 127) / 128, 2);
    const int gblocks = (int)(((long long)N * 64 + 255) / 256);

    // ---- layer 1 ----
    gemm_mfma<<<ggrid, 256, 0, stream>>>(Xb, Wp1, P, N, 256);
    gather_combine<<<gblocks, 256, 0, stream>>>(P, ROWP, CSRC, INV, H, N);

    // ---- layer 2 ----
    gemm_mfma<<<ggrid, 256, 0, stream>>>(H, Wp2, P, N, 128);
    gather_combine<<<gblocks, 256, 0, stream>>>(P, ROWP, CSRC, INV, H, N);

    // ---- head ----
    mlp_head_mfma<<<(N + 63) / 64, 256, 0, stream>>>(H, Wb, mlpb, (float*)d_out, N);
}

// Round 7
// 578.684 us; speedup vs baseline: 15.4803x; 1.0660x over previous
//
#include <hip/hip_runtime.h>
#include <hip/hip_bf16.h>

#define NFEAT 256
#define NHID  128
#define NCLASS 40

typedef __attribute__((ext_vector_type(8))) short short8;
typedef __attribute__((ext_vector_type(4))) float float4v;

__device__ __forceinline__ unsigned short f2bf(float f) {
    union { float f; unsigned u; } v; v.f = f;
    unsigned r = v.u + 0x7fff + ((v.u >> 16) & 1);   // RNE
    return (unsigned short)(r >> 16);
}
__device__ __forceinline__ float bflo(unsigned u) { return __uint_as_float(u << 16); }
__device__ __forceinline__ float bfhi(unsigned u) { return __uint_as_float(u & 0xffff0000u); }
__device__ __forceinline__ unsigned packbf(float a, float b) {
    return (unsigned)f2bf(a) | ((unsigned)f2bf(b) << 16);
}

#define TILE_E 8192   // edges per binning block

// ---- K1: per-block LDS histogram of row>>9 buckets -> few global atomics ----
__global__ __launch_bounds__(256) void bin_hist(const int* __restrict__ rows,
                                                int* __restrict__ ghist, int E, int nbuck) {
    __shared__ int hh[256];
    int t = threadIdx.x;
    hh[t] = 0;
    __syncthreads();
    int e0 = blockIdx.x * TILE_E;
    #pragma unroll 4
    for (int it = 0; it < TILE_E / 256; ++it) {
        int e = e0 + it * 256 + t;
        if (e < E) atomicAdd(&hh[rows[e] >> 9], 1);
    }
    __syncthreads();
    if (t < nbuck && hh[t]) atomicAdd(&ghist[t], hh[t]);
}

// ---- K2: scan bucket counts -> bases + cursors; row_ptr[N] = E ----
__global__ void scan_buckets(const int* __restrict__ ghist, int* __restrict__ gbase,
                             int* __restrict__ gcur, int* __restrict__ row_ptr,
                             int nbuck, int N, int E) {
    __shared__ int s[256];
    int t = threadIdx.x;
    int v = (t < nbuck) ? ghist[t] : 0;
    s[t] = v;
    __syncthreads();
    for (int off = 1; off < 256; off <<= 1) {
        int tmp = (t >= off) ? s[t - off] : 0;
        __syncthreads();
        s[t] += tmp;
        __syncthreads();
    }
    int excl = s[t] - v;
    if (t < nbuck) { gbase[t] = excl; gcur[t] = excl; }
    if (t == 0) { gbase[nbuck] = E; row_ptr[N] = E; }
}

// ---- K3: re-histogram tile, reserve per-bucket chunks, scatter packed pairs ----
// packed entry: (row & 511) << 17 | col   (col < 2^17)
__global__ __launch_bounds__(256) void bin_scatter(const int* __restrict__ rows,
                                                   const int* __restrict__ cols,
                                                   int* __restrict__ gcur,
                                                   unsigned* __restrict__ binned, int E, int nbuck) {
    __shared__ int hh[256];
    __shared__ int lbase[256];
    __shared__ int lcur[256];
    int t = threadIdx.x;
    hh[t] = 0;
    __syncthreads();
    int e0 = blockIdx.x * TILE_E;
    #pragma unroll 4
    for (int it = 0; it < TILE_E / 256; ++it) {
        int e = e0 + it * 256 + t;
        if (e < E) atomicAdd(&hh[rows[e] >> 9], 1);
    }
    __syncthreads();
    if (t < nbuck) {
        lbase[t] = hh[t] ? atomicAdd(&gcur[t], hh[t]) : 0;
        lcur[t] = 0;
    }
    __syncthreads();
    #pragma unroll 4
    for (int it = 0; it < TILE_E / 256; ++it) {
        int e = e0 + it * 256 + t;
        if (e < E) {
            int r = rows[e];
            int b = r >> 9;
            int dst = lbase[b] + atomicAdd(&lcur[b], 1);
            binned[dst] = ((unsigned)(r & 511) << 17) | (unsigned)cols[e];
        }
    }
}

// ---- K4: one block per 512-row window: degrees+scan -> row_ptr, inv_deg, CSR cols ----
__global__ __launch_bounds__(256) void fill_win(const unsigned* __restrict__ binned,
                                                const int* __restrict__ gbase,
                                                int* __restrict__ row_ptr,
                                                float* __restrict__ inv,
                                                int* __restrict__ csr_cols, int N) {
    __shared__ int h[512];
    __shared__ int ps[256];
    __shared__ int lcur[512];
    int t = threadIdx.x;
    int w = blockIdx.x;
    int r0 = w << 9;
    h[t] = 0; h[t + 256] = 0;
    __syncthreads();
    int beg = gbase[w], end = gbase[w + 1];
    for (int e = beg + t; e < end; e += 256)
        atomicAdd(&h[binned[e] >> 17], 1);
    __syncthreads();
    int pair = h[2 * t] + h[2 * t + 1];
    ps[t] = pair;
    __syncthreads();
    for (int off = 1; off < 256; off <<= 1) {
        int tmp = (t >= off) ? ps[t - off] : 0;
        __syncthreads();
        ps[t] += tmp;
        __syncthreads();
    }
    int base0 = beg + ps[t] - pair;
    int base1 = base0 + h[2 * t];
    int r_a = r0 + 2 * t, r_b = r0 + 2 * t + 1;
    if (r_a < N) { row_ptr[r_a] = base0; inv[r_a] = 1.0f / ((float)h[2 * t] + 1.0f); }
    if (r_b < N) { row_ptr[r_b] = base1; inv[r_b] = 1.0f / ((float)h[2 * t + 1] + 1.0f); }
    lcur[2 * t] = base0;
    lcur[2 * t + 1] = base1;
    __syncthreads();
    for (int e = beg + t; e < end; e += 256) {
        unsigned v = binned[e];
        int idx = atomicAdd(&lcur[v >> 17], 1);
        csr_cols[idx] = (int)(v & 0x1FFFFu);
    }
}

// ---------------- fp32 -> bf16 conversion of x ----------------
__global__ void conv_bf16(const float* __restrict__ in, unsigned short* __restrict__ out, long long n4) {
    long long i = (long long)blockIdx.x * blockDim.x + threadIdx.x;
    if (i >= n4) return;
    float4 v = *reinterpret_cast<const float4*>(&in[i * 4]);
    ushort4 o;
    o.x = f2bf(v.x); o.y = f2bf(v.y); o.z = f2bf(v.z); o.w = f2bf(v.w);
    *reinterpret_cast<ushort4*>(&out[i * 4]) = o;
}

// ---------------- fused weight repack (W1, W2 -> K-panels; Wm -> padded bf16) ----------------
// Wp layout: [k0/32][o(256)][k(32)]
__global__ __launch_bounds__(256) void repack_all(const float* __restrict__ W1,
                                                  const float* __restrict__ W2,
                                                  const float* __restrict__ Wm,
                                                  unsigned short* __restrict__ Wp1,
                                                  unsigned short* __restrict__ Wp2,
                                                  unsigned short* __restrict__ Wb) {
    int b = blockIdx.x, t = threadIdx.x;
    if (b < 256) {                       // W1: o=b (0..255), k=t (0..255)
        float v = (b < 128) ? W1[b * 512 + t] : W1[(b - 128) * 512 + 256 + t];
        Wp1[(size_t)(t >> 5) * 256 * 32 + b * 32 + (t & 31)] = f2bf(v);
    } else if (b < 512) {                // W2: o=b-256 (0..255), k=t (0..127)
        int o = b - 256;
        if (t < 128) {
            float v = (o < 128) ? W2[o * 256 + t] : W2[(o - 128) * 256 + 128 + t];
            Wp2[(size_t)(t >> 5) * 256 * 32 + o * 32 + (t & 31)] = f2bf(v);
        }
    } else {                             // Wm: o=b-512 (0..47), k=t (0..127)
        int o = b - 512;
        if (t < 128) Wb[o * 128 + t] = (o < NCLASS) ? f2bf(Wm[o * 128 + t]) : 0;
    }
}

// ---------------- bf16 MFMA GEMM: P[M x 256] = Xb[M x K] @ W (packed) ----------------
// grid = (2, Mblocks): n-blocks sharing an A-panel dispatch back-to-back -> A L2-hot.
#define LDK 40
__global__ __launch_bounds__(256) void gemm_mfma(const unsigned short* __restrict__ Xb,
                                                 const unsigned short* __restrict__ Wp,
                                                 unsigned short* __restrict__ P,
                                                 int M, int K) {
    __shared__ unsigned short sA[128][LDK];
    __shared__ unsigned short sB[128][LDK];
    const int t    = threadIdx.x;
    const int lane = t & 63;
    const int wave = t >> 6;
    const int m0 = blockIdx.y * 128;
    const int n0 = blockIdx.x * 128;
    const int wm = (wave >> 1) * 64;
    const int wn = (wave & 1) * 64;

    const int lrow = t >> 2;
    const int lk   = (t & 3) * 8;
    const int r15  = lane & 15;
    const int k8   = (lane >> 4) * 8;

    float4v acc[4][4] = {{{0.f,0.f,0.f,0.f}}};

    for (int k0 = 0; k0 < K; k0 += 32) {
        #pragma unroll
        for (int it = 0; it < 2; ++it) {
            int r  = lrow + it * 64;
            int gm = m0 + r;
            float4 v = make_float4(0.f, 0.f, 0.f, 0.f);
            if (gm < M) v = *reinterpret_cast<const float4*>(&Xb[(size_t)gm * K + k0 + lk]);
            *reinterpret_cast<float4*>(&sA[r][lk]) = v;
        }
        const unsigned short* pan = Wp + ((size_t)(k0 >> 5) * 256 + n0) * 32;
        #pragma unroll
        for (int it = 0; it < 2; ++it) {
            int r = lrow + it * 64;
            float4 v = *reinterpret_cast<const float4*>(&pan[(size_t)r * 32 + lk]);
            *reinterpret_cast<float4*>(&sB[r][lk]) = v;
        }
        __syncthreads();

        short8 aF[4], bF[4];
        #pragma unroll
        for (int i = 0; i < 4; ++i)
            aF[i] = *reinterpret_cast<const short8*>(&sA[wm + i * 16 + r15][k8]);
        #pragma unroll
        for (int j = 0; j < 4; ++j)
            bF[j] = *reinterpret_cast<const short8*>(&sB[wn + j * 16 + r15][k8]);
        #pragma unroll
        for (int i = 0; i < 4; ++i)
            #pragma unroll
            for (int j = 0; j < 4; ++j)
                acc[i][j] = __builtin_amdgcn_mfma_f32_16x16x32_bf16(aF[i], bF[j], acc[i][j], 0, 0, 0);
        __syncthreads();
    }

    #pragma unroll
    for (int i = 0; i < 4; ++i) {
        #pragma unroll
        for (int r = 0; r < 4; ++r) {
            int row = m0 + wm + i * 16 + (lane >> 4) * 4 + r;
            if (row < M) {
                #pragma unroll
                for (int j = 0; j < 4; ++j)
                    P[(size_t)row * 256 + n0 + wn + j * 16 + r15] = f2bf(acc[i][j][r]);
            }
        }
    }
}

// ---------------- gather-aggregate + combine + relu: one wave per node ----------------
// 4 groups x 4-deep unroll = 16 independent 1KB gathers in flight per wave.
__global__ __launch_bounds__(256) void gather_combine(const unsigned short* __restrict__ P,
                                                      const int* __restrict__ row_ptr,
                                                      const int* __restrict__ csr_cols,
                                                      const float* __restrict__ invdeg,
                                                      unsigned short* __restrict__ H, int N) {
    int node = (blockIdx.x * blockDim.x + threadIdx.x) >> 6;
    if (node >= N) return;
    int lane = threadIdx.x & 63;
    int grp  = lane >> 4;
    int l16  = lane & 15;
    int beg = row_ptr[node], end = row_ptr[node + 1];

    float a0=0,a1=0,a2=0,a3=0,a4=0,a5=0,a6=0,a7=0;
    for (int p0 = beg + grp; p0 < end; p0 += 16) {
        int last = end - 1;
        int pB = p0 + 4, pC = p0 + 8, pD = p0 + 12;
        int cA = csr_cols[p0];
        int cB = csr_cols[min(pB, last)];
        int cC = csr_cols[min(pC, last)];
        int cD = csr_cols[min(pD, last)];
        uint4 uA = *reinterpret_cast<const uint4*>(&P[(size_t)cA * 256 + 128 + l16 * 8]);
        uint4 uB = *reinterpret_cast<const uint4*>(&P[(size_t)cB * 256 + 128 + l16 * 8]);
        uint4 uC = *reinterpret_cast<const uint4*>(&P[(size_t)cC * 256 + 128 + l16 * 8]);
        uint4 uD = *reinterpret_cast<const uint4*>(&P[(size_t)cD * 256 + 128 + l16 * 8]);
        if (pB >= end) { uB.x = uB.y = uB.z = uB.w = 0; }
        if (pC >= end) { uC.x = uC.y = uC.z = uC.w = 0; }
        if (pD >= end) { uD.x = uD.y = uD.z = uD.w = 0; }
        a0 += bflo(uA.x) + bflo(uB.x) + bflo(uC.x) + bflo(uD.x);
        a1 += bfhi(uA.x) + bfhi(uB.x) + bfhi(uC.x) + bfhi(uD.x);
        a2 += bflo(uA.y) + bflo(uB.y) + bflo(uC.y) + bflo(uD.y);
        a3 += bfhi(uA.y) + bfhi(uB.y) + bfhi(uC.y) + bfhi(uD.y);
        a4 += bflo(uA.z) + bflo(uB.z) + bflo(uC.z) + bflo(uD.z);
        a5 += bfhi(uA.z) + bfhi(uB.z) + bfhi(uC.z) + bfhi(uD.z);
        a6 += bflo(uA.w) + bflo(uB.w) + bflo(uC.w) + bflo(uD.w);
        a7 += bfhi(uA.w) + bfhi(uB.w) + bfhi(uC.w) + bfhi(uD.w);
    }
    a0 += __shfl_xor(a0, 16); a1 += __shfl_xor(a1, 16);
    a2 += __shfl_xor(a2, 16); a3 += __shfl_xor(a3, 16);
    a4 += __shfl_xor(a4, 16); a5 += __shfl_xor(a5, 16);
    a6 += __shfl_xor(a6, 16); a7 += __shfl_xor(a7, 16);
    a0 += __shfl_xor(a0, 32); a1 += __shfl_xor(a1, 32);
    a2 += __shfl_xor(a2, 32); a3 += __shfl_xor(a3, 32);
    a4 += __shfl_xor(a4, 32); a5 += __shfl_xor(a5, 32);
    a6 += __shfl_xor(a6, 32); a7 += __shfl_xor(a7, 32);

    if (grp == 0) {
        float id = invdeg[node];
        uint4 us = *reinterpret_cast<const uint4*>(&P[(size_t)node * 256 + l16 * 8]);
        float h0 = fmaxf(fmaf(a0, id, bflo(us.x)), 0.f);
        float h1 = fmaxf(fmaf(a1, id, bfhi(us.x)), 0.f);
        float h2 = fmaxf(fmaf(a2, id, bflo(us.y)), 0.f);
        float h3 = fmaxf(fmaf(a3, id, bfhi(us.y)), 0.f);
        float h4 = fmaxf(fmaf(a4, id, bflo(us.z)), 0.f);
        float h5 = fmaxf(fmaf(a5, id, bfhi(us.z)), 0.f);
        float h6 = fmaxf(fmaf(a6, id, bflo(us.w)), 0.f);
        float h7 = fmaxf(fmaf(a7, id, bfhi(us.w)), 0.f);
        uint4 o;
        o.x = packbf(h0, h1); o.y = packbf(h2, h3);
        o.z = packbf(h4, h5); o.w = packbf(h6, h7);
        *reinterpret_cast<uint4*>(&H[(size_t)node * 128 + l16 * 8]) = o;
    }
}

// ---------------- MFMA head: logits = H @ Wb^T (+bias), fused log_softmax ----------------
__global__ __launch_bounds__(256) void mlp_head_mfma(const unsigned short* __restrict__ H,
                                                     const unsigned short* __restrict__ Wb,
                                                     const float* __restrict__ bm,
                                                     float* __restrict__ out, int N) {
    __shared__ unsigned short sW[48 * 128];   // 12 KB
    int t = threadIdx.x;
    for (int i = t; i < 48 * 128 / 2; i += 256)
        ((unsigned*)sW)[i] = ((const unsigned*)Wb)[i];
    __syncthreads();

    const int wave = t >> 6, lane = t & 63;
    const int m0 = blockIdx.x * 64 + wave * 16;
    if (m0 >= N) return;
    const int r15 = lane & 15;
    const int k8  = (lane >> 4) * 8;
    const int arow = min(m0 + r15, N - 1);

    float4v acc[3] = {{0.f,0.f,0.f,0.f},{0.f,0.f,0.f,0.f},{0.f,0.f,0.f,0.f}};
    #pragma unroll
    for (int k0 = 0; k0 < 128; k0 += 32) {
        short8 a = *reinterpret_cast<const short8*>(&H[(size_t)arow * 128 + k0 + k8]);
        #pragma unroll
        for (int f = 0; f < 3; ++f) {
            short8 b = *reinterpret_cast<const short8*>(&sW[(f * 16 + r15) * 128 + k0 + k8]);
            acc[f] = __builtin_amdgcn_mfma_f32_16x16x32_bf16(a, b, acc[f], 0, 0, 0);
        }
    }

    float bias[3]; bool cv[3];
    #pragma unroll
    for (int f = 0; f < 3; ++f) {
        int c = f * 16 + r15;
        cv[f] = (c < NCLASS);
        bias[f] = cv[f] ? bm[c] : 0.f;
    }
    #pragma unroll
    for (int r = 0; r < 4; ++r) {
        int node = m0 + (lane >> 4) * 4 + r;
        float lg[3];
        float m = -1e30f;
        #pragma unroll
        for (int f = 0; f < 3; ++f) {
            lg[f] = cv[f] ? (acc[f][r] + bias[f]) : -1e30f;
            m = fmaxf(m, lg[f]);
        }
        m = fmaxf(m, __shfl_xor(m, 1));
        m = fmaxf(m, __shfl_xor(m, 2));
        m = fmaxf(m, __shfl_xor(m, 4));
        m = fmaxf(m, __shfl_xor(m, 8));
        float s = 0.f;
        #pragma unroll
        for (int f = 0; f < 3; ++f) s += cv[f] ? __expf(lg[f] - m) : 0.f;
        s += __shfl_xor(s, 1);
        s += __shfl_xor(s, 2);
        s += __shfl_xor(s, 4);
        s += __shfl_xor(s, 8);
        float ls = __logf(s);
        if (node < N) {
            #pragma unroll
            for (int f = 0; f < 3; ++f)
                if (cv[f]) out[(size_t)node * NCLASS + f * 16 + r15] = lg[f] - m - ls;
        }
    }
}

extern "C" void kernel_launch(void* const* d_in, const int* in_sizes, int n_in,
                              void* d_out, int out_size, void* d_ws, size_t ws_size,
                              hipStream_t stream) {
    const float* x    = (const float*)d_in[0];
    const float* W1   = (const float*)d_in[1];
    const float* W2   = (const float*)d_in[2];
    const float* mlpW = (const float*)d_in[3];
    const float* mlpb = (const float*)d_in[4];
    const int*   rows = (const int*)d_in[5];
    const int*   cols = (const int*)d_in[6];

    const int N = in_sizes[0] / NFEAT;   // 100000
    const int E = in_sizes[5];           // 3200000

    char* ws = (char*)d_ws;
    size_t off = 0;
    auto alloc = [&](size_t bytes) -> void* {
        void* p = ws + off;
        off = (off + bytes + 255) & ~(size_t)255;
        return p;
    };
    unsigned short* Xb  = (unsigned short*)alloc((size_t)N * 256 * 2);
    unsigned short* P   = (unsigned short*)alloc((size_t)N * 256 * 2);
    unsigned short* H   = (unsigned short*)alloc((size_t)N * 128 * 2);
    float* INV    = (float*)alloc((size_t)N * 4);
    int*   ROWP   = (int*)  alloc((size_t)(N + 1) * 4);
    int*   CSRC   = (int*)  alloc((size_t)E * 4);
    unsigned* BINNED = (unsigned*)alloc((size_t)E * 4);
    int*   GHIST  = (int*)  alloc((size_t)256 * 4);
    int*   GBASE  = (int*)  alloc((size_t)257 * 4);
    int*   GCUR   = (int*)  alloc((size_t)256 * 4);
    unsigned short* Wp1 = (unsigned short*)alloc((size_t)256 * 256 * 2);
    unsigned short* Wp2 = (unsigned short*)alloc((size_t)128 * 256 * 2);
    unsigned short* Wb  = (unsigned short*)alloc((size_t)48 * 128 * 2);

    const int nbuck = (N + 511) >> 9;              // 196
    const int nblk  = (E + TILE_E - 1) / TILE_E;   // 391

    // ---- CSR build via LDS-histogram binning (also produces row_ptr + inv_deg) ----
    hipMemsetAsync(GHIST, 0, 256 * 4, stream);
    bin_hist<<<nblk, 256, 0, stream>>>(rows, GHIST, E, nbuck);
    scan_buckets<<<1, 256, 0, stream>>>(GHIST, GBASE, GCUR, ROWP, nbuck, N, E);
    bin_scatter<<<nblk, 256, 0, stream>>>(rows, cols, GCUR, BINNED, E, nbuck);
    fill_win<<<nbuck, 256, 0, stream>>>(BINNED, GBASE, ROWP, INV, CSRC, N);

    // ---- dtype prep ----
    long long n4 = (long long)N * 256 / 4;
    conv_bf16<<<(int)((n4 + 255) / 256), 256, 0, stream>>>(x, Xb, n4);
    repack_all<<<560, 256, 0, stream>>>(W1, W2, mlpW, Wp1, Wp2, Wb);

    dim3 ggrid(2, (N + 127) / 128);
    const int gblocks = (int)(((long long)N * 64 + 255) / 256);

    // ---- layer 1 ----
    gemm_mfma<<<ggrid, 256, 0, stream>>>(Xb, Wp1, P, N, 256);
    gather_combine<<<gblocks, 256, 0, stream>>>(P, ROWP, CSRC, INV, H, N);

    // ---- layer 2 ----
    gemm_mfma<<<ggrid, 256, 0, stream>>>(H, Wp2, P, N, 128);
    gather_combine<<<gblocks, 256, 0, stream>>>(P, ROWP, CSRC, INV, H, N);

    // ---- head ----
    mlp_head_mfma<<<(N + 63) / 64, 256, 0, stream>>>(H, Wb, mlpb, (float*)d_out, N);
}

// Round 8
// 577.859 us; speedup vs baseline: 15.5024x; 1.0014x over previous
//
#include <hip/hip_runtime.h>
#include <hip/hip_bf16.h>

#define NFEAT 256
#define NHID  128
#define NCLASS 40

typedef __attribute__((ext_vector_type(8))) short short8;
typedef __attribute__((ext_vector_type(4))) float float4v;

__device__ __forceinline__ unsigned short f2bf(float f) {
    union { float f; unsigned u; } v; v.f = f;
    unsigned r = v.u + 0x7fff + ((v.u >> 16) & 1);   // RNE
    return (unsigned short)(r >> 16);
}
__device__ __forceinline__ float bflo(unsigned u) { return __uint_as_float(u << 16); }
__device__ __forceinline__ float bfhi(unsigned u) { return __uint_as_float(u & 0xffff0000u); }
__device__ __forceinline__ unsigned packbf(float a, float b) {
    return (unsigned)f2bf(a) | ((unsigned)f2bf(b) << 16);
}

// async global->LDS, 16B per lane; LDS dest = wave-uniform base + lane*16
__device__ __forceinline__ void ld_g2l16(const unsigned short* gp, unsigned short* lp) {
    __builtin_amdgcn_global_load_lds((const __attribute__((address_space(1))) unsigned short*)gp,
                                     (__attribute__((address_space(3))) unsigned short*)lp,
                                     16, 0, 0);
}

#define TILE_E 8192   // edges per binning block

// ---- K1: per-block LDS histogram of row>>9 buckets -> few global atomics ----
__global__ __launch_bounds__(256) void bin_hist(const int* __restrict__ rows,
                                                int* __restrict__ ghist, int E, int nbuck) {
    __shared__ int hh[256];
    int t = threadIdx.x;
    hh[t] = 0;
    __syncthreads();
    int e0 = blockIdx.x * TILE_E;
    #pragma unroll 4
    for (int it = 0; it < TILE_E / 256; ++it) {
        int e = e0 + it * 256 + t;
        if (e < E) atomicAdd(&hh[rows[e] >> 9], 1);
    }
    __syncthreads();
    if (t < nbuck && hh[t]) atomicAdd(&ghist[t], hh[t]);
}

// ---- K2: scan bucket counts -> bases + cursors; row_ptr[N] = E ----
__global__ void scan_buckets(const int* __restrict__ ghist, int* __restrict__ gbase,
                             int* __restrict__ gcur, int* __restrict__ row_ptr,
                             int nbuck, int N, int E) {
    __shared__ int s[256];
    int t = threadIdx.x;
    int v = (t < nbuck) ? ghist[t] : 0;
    s[t] = v;
    __syncthreads();
    for (int off = 1; off < 256; off <<= 1) {
        int tmp = (t >= off) ? s[t - off] : 0;
        __syncthreads();
        s[t] += tmp;
        __syncthreads();
    }
    int excl = s[t] - v;
    if (t < nbuck) { gbase[t] = excl; gcur[t] = excl; }
    if (t == 0) { gbase[nbuck] = E; row_ptr[N] = E; }
}

// ---- K3: re-histogram tile, reserve per-bucket chunks, scatter packed pairs ----
// packed entry: (row & 511) << 17 | col   (col < 2^17)
__global__ __launch_bounds__(256) void bin_scatter(const int* __restrict__ rows,
                                                   const int* __restrict__ cols,
                                                   int* __restrict__ gcur,
                                                   unsigned* __restrict__ binned, int E, int nbuck) {
    __shared__ int hh[256];
    __shared__ int lbase[256];
    __shared__ int lcur[256];
    int t = threadIdx.x;
    hh[t] = 0;
    __syncthreads();
    int e0 = blockIdx.x * TILE_E;
    #pragma unroll 4
    for (int it = 0; it < TILE_E / 256; ++it) {
        int e = e0 + it * 256 + t;
        if (e < E) atomicAdd(&hh[rows[e] >> 9], 1);
    }
    __syncthreads();
    if (t < nbuck) {
        lbase[t] = hh[t] ? atomicAdd(&gcur[t], hh[t]) : 0;
        lcur[t] = 0;
    }
    __syncthreads();
    #pragma unroll 4
    for (int it = 0; it < TILE_E / 256; ++it) {
        int e = e0 + it * 256 + t;
        if (e < E) {
            int r = rows[e];
            int b = r >> 9;
            int dst = lbase[b] + atomicAdd(&lcur[b], 1);
            binned[dst] = ((unsigned)(r & 511) << 17) | (unsigned)cols[e];
        }
    }
}

// ---- K4: one block per 512-row window: degrees+scan -> row_ptr, inv_deg, CSR cols ----
__global__ __launch_bounds__(256) void fill_win(const unsigned* __restrict__ binned,
                                                const int* __restrict__ gbase,
                                                int* __restrict__ row_ptr,
                                                float* __restrict__ inv,
                                                int* __restrict__ csr_cols, int N) {
    __shared__ int h[512];
    __shared__ int ps[256];
    __shared__ int lcur[512];
    int t = threadIdx.x;
    int w = blockIdx.x;
    int r0 = w << 9;
    h[t] = 0; h[t + 256] = 0;
    __syncthreads();
    int beg = gbase[w], end = gbase[w + 1];
    for (int e = beg + t; e < end; e += 256)
        atomicAdd(&h[binned[e] >> 17], 1);
    __syncthreads();
    int pair = h[2 * t] + h[2 * t + 1];
    ps[t] = pair;
    __syncthreads();
    for (int off = 1; off < 256; off <<= 1) {
        int tmp = (t >= off) ? ps[t - off] : 0;
        __syncthreads();
        ps[t] += tmp;
        __syncthreads();
    }
    int base0 = beg + ps[t] - pair;
    int base1 = base0 + h[2 * t];
    int r_a = r0 + 2 * t, r_b = r0 + 2 * t + 1;
    if (r_a < N) { row_ptr[r_a] = base0; inv[r_a] = 1.0f / ((float)h[2 * t] + 1.0f); }
    if (r_b < N) { row_ptr[r_b] = base1; inv[r_b] = 1.0f / ((float)h[2 * t + 1] + 1.0f); }
    lcur[2 * t] = base0;
    lcur[2 * t + 1] = base1;
    __syncthreads();
    for (int e = beg + t; e < end; e += 256) {
        unsigned v = binned[e];
        int idx = atomicAdd(&lcur[v >> 17], 1);
        csr_cols[idx] = (int)(v & 0x1FFFFu);
    }
}

// ---------------- fp32 -> bf16 conversion of x ----------------
__global__ void conv_bf16(const float* __restrict__ in, unsigned short* __restrict__ out, long long n4) {
    long long i = (long long)blockIdx.x * blockDim.x + threadIdx.x;
    if (i >= n4) return;
    float4 v = *reinterpret_cast<const float4*>(&in[i * 4]);
    ushort4 o;
    o.x = f2bf(v.x); o.y = f2bf(v.y); o.z = f2bf(v.z); o.w = f2bf(v.w);
    *reinterpret_cast<ushort4*>(&out[i * 4]) = o;
}

// ---------------- fused weight repack (W1, W2 -> K-panels; Wm -> padded bf16) ----------------
// Wp layout: [k0/32][o(256)][k(32)]
__global__ __launch_bounds__(256) void repack_all(const float* __restrict__ W1,
                                                  const float* __restrict__ W2,
                                                  const float* __restrict__ Wm,
                                                  unsigned short* __restrict__ Wp1,
                                                  unsigned short* __restrict__ Wp2,
                                                  unsigned short* __restrict__ Wb) {
    int b = blockIdx.x, t = threadIdx.x;
    if (b < 256) {                       // W1: o=b (0..255), k=t (0..255)
        float v = (b < 128) ? W1[b * 512 + t] : W1[(b - 128) * 512 + 256 + t];
        Wp1[(size_t)(t >> 5) * 256 * 32 + b * 32 + (t & 31)] = f2bf(v);
    } else if (b < 512) {                // W2: o=b-256 (0..255), k=t (0..127)
        int o = b - 256;
        if (t < 128) {
            float v = (o < 128) ? W2[o * 256 + t] : W2[(o - 128) * 256 + 128 + t];
            Wp2[(size_t)(t >> 5) * 256 * 32 + o * 32 + (t & 31)] = f2bf(v);
        }
    } else {                             // Wm: o=b-512 (0..47), k=t (0..127)
        int o = b - 512;
        if (t < 128) Wb[o * 128 + t] = (o < NCLASS) ? f2bf(Wm[o * 128 + t]) : 0;
    }
}

// ---------------- bf16 MFMA GEMM (m97 structure): P[M x 256] = Xb[M x K] @ Wp ----------------
// BM=BN=128, BK=32; unpadded [128][32] LDS; staging via global_load_lds dwordx4.
// NOTE: A-tail of the last M-block reads past the matrix into adjacent ws regions —
// safe (within d_ws), and those rows' outputs are discarded by the row<M store mask.
__global__ __launch_bounds__(256) void gemm_mfma(const unsigned short* __restrict__ Xb,
                                                 const unsigned short* __restrict__ Wp,
                                                 unsigned short* __restrict__ P,
                                                 int M, int K) {
    __shared__ unsigned short sA[128 * 32];
    __shared__ unsigned short sB[128 * 32];
    const int t    = threadIdx.x;
    const int lane = t & 63;
    const int wave = t >> 6;
    const int m0 = blockIdx.y * 128;
    const int n0 = blockIdx.x * 128;
    const int wm = (wave >> 1) * 64;
    const int wn = (wave & 1) * 64;

    const int r15 = lane & 15;
    const int k8  = (lane >> 4) * 8;
    const int srow = lane >> 2;        // 0..15 within a 16-row wave slab
    const int skb  = (lane & 3) * 8;   // 0,8,16,24 (elements)

    float4v acc[4][4] = {{{0.f,0.f,0.f,0.f}}};

    for (int k0 = 0; k0 < K; k0 += 32) {
        const unsigned short* pan = Wp + ((size_t)(k0 >> 5) * 256 + n0) * 32;
        #pragma unroll
        for (int it = 0; it < 2; ++it) {
            int slab = it * 64 + wave * 16;                 // wave-uniform
            const unsigned short* gA = Xb + (size_t)(m0 + slab + srow) * K + k0 + skb;
            ld_g2l16(gA, &sA[slab * 32]);
            const unsigned short* gB = pan + (size_t)(slab + srow) * 32 + skb;
            ld_g2l16(gB, &sB[slab * 32]);
        }
        __syncthreads();

        short8 aF[4], bF[4];
        #pragma unroll
        for (int i = 0; i < 4; ++i)
            aF[i] = *reinterpret_cast<const short8*>(&sA[(wm + i * 16 + r15) * 32 + k8]);
        #pragma unroll
        for (int j = 0; j < 4; ++j)
            bF[j] = *reinterpret_cast<const short8*>(&sB[(wn + j * 16 + r15) * 32 + k8]);
        #pragma unroll
        for (int i = 0; i < 4; ++i)
            #pragma unroll
            for (int j = 0; j < 4; ++j)
                acc[i][j] = __builtin_amdgcn_mfma_f32_16x16x32_bf16(aF[i], bF[j], acc[i][j], 0, 0, 0);
        __syncthreads();
    }

    #pragma unroll
    for (int i = 0; i < 4; ++i) {
        #pragma unroll
        for (int r = 0; r < 4; ++r) {
            int row = m0 + wm + i * 16 + (lane >> 4) * 4 + r;
            if (row < M) {
                #pragma unroll
                for (int j = 0; j < 4; ++j)
                    P[(size_t)row * 256 + n0 + wn + j * 16 + r15] = f2bf(acc[i][j][r]);
            }
        }
    }
}

// ---------------- gather-aggregate + combine + relu: one wave per node ----------------
// 4 groups x 4-deep clamp-free steady loop = 16 independent 1KB gathers in flight.
__global__ __launch_bounds__(256) void gather_combine(const unsigned short* __restrict__ P,
                                                      const int* __restrict__ row_ptr,
                                                      const int* __restrict__ csr_cols,
                                                      const float* __restrict__ invdeg,
                                                      unsigned short* __restrict__ H, int N) {
    int node = (blockIdx.x * blockDim.x + threadIdx.x) >> 6;
    if (node >= N) return;
    int lane = threadIdx.x & 63;
    int grp  = lane >> 4;
    int l16  = lane & 15;
    int beg = row_ptr[node], end = row_ptr[node + 1];

    float a0=0,a1=0,a2=0,a3=0,a4=0,a5=0,a6=0,a7=0;
    int p0 = beg + grp;
    for (; p0 + 12 < end; p0 += 16) {
        int cA = csr_cols[p0];
        int cB = csr_cols[p0 + 4];
        int cC = csr_cols[p0 + 8];
        int cD = csr_cols[p0 + 12];
        uint4 uA = *reinterpret_cast<const uint4*>(&P[(size_t)cA * 256 + 128 + l16 * 8]);
        uint4 uB = *reinterpret_cast<const uint4*>(&P[(size_t)cB * 256 + 128 + l16 * 8]);
        uint4 uC = *reinterpret_cast<const uint4*>(&P[(size_t)cC * 256 + 128 + l16 * 8]);
        uint4 uD = *reinterpret_cast<const uint4*>(&P[(size_t)cD * 256 + 128 + l16 * 8]);
        a0 += bflo(uA.x) + bflo(uB.x) + bflo(uC.x) + bflo(uD.x);
        a1 += bfhi(uA.x) + bfhi(uB.x) + bfhi(uC.x) + bfhi(uD.x);
        a2 += bflo(uA.y) + bflo(uB.y) + bflo(uC.y) + bflo(uD.y);
        a3 += bfhi(uA.y) + bfhi(uB.y) + bfhi(uC.y) + bfhi(uD.y);
        a4 += bflo(uA.z) + bflo(uB.z) + bflo(uC.z) + bflo(uD.z);
        a5 += bfhi(uA.z) + bfhi(uB.z) + bfhi(uC.z) + bfhi(uD.z);
        a6 += bflo(uA.w) + bflo(uB.w) + bflo(uC.w) + bflo(uD.w);
        a7 += bfhi(uA.w) + bfhi(uB.w) + bfhi(uC.w) + bfhi(uD.w);
    }
    for (; p0 < end; p0 += 4) {
        int c = csr_cols[p0];
        uint4 u = *reinterpret_cast<const uint4*>(&P[(size_t)c * 256 + 128 + l16 * 8]);
        a0 += bflo(u.x); a1 += bfhi(u.x);
        a2 += bflo(u.y); a3 += bfhi(u.y);
        a4 += bflo(u.z); a5 += bfhi(u.z);
        a6 += bflo(u.w); a7 += bfhi(u.w);
    }
    a0 += __shfl_xor(a0, 16); a1 += __shfl_xor(a1, 16);
    a2 += __shfl_xor(a2, 16); a3 += __shfl_xor(a3, 16);
    a4 += __shfl_xor(a4, 16); a5 += __shfl_xor(a5, 16);
    a6 += __shfl_xor(a6, 16); a7 += __shfl_xor(a7, 16);
    a0 += __shfl_xor(a0, 32); a1 += __shfl_xor(a1, 32);
    a2 += __shfl_xor(a2, 32); a3 += __shfl_xor(a3, 32);
    a4 += __shfl_xor(a4, 32); a5 += __shfl_xor(a5, 32);
    a6 += __shfl_xor(a6, 32); a7 += __shfl_xor(a7, 32);

    if (grp == 0) {
        float id = invdeg[node];
        uint4 us = *reinterpret_cast<const uint4*>(&P[(size_t)node * 256 + l16 * 8]);
        float h0 = fmaxf(fmaf(a0, id, bflo(us.x)), 0.f);
        float h1 = fmaxf(fmaf(a1, id, bfhi(us.x)), 0.f);
        float h2 = fmaxf(fmaf(a2, id, bflo(us.y)), 0.f);
        float h3 = fmaxf(fmaf(a3, id, bfhi(us.y)), 0.f);
        float h4 = fmaxf(fmaf(a4, id, bflo(us.z)), 0.f);
        float h5 = fmaxf(fmaf(a5, id, bfhi(us.z)), 0.f);
        float h6 = fmaxf(fmaf(a6, id, bflo(us.w)), 0.f);
        float h7 = fmaxf(fmaf(a7, id, bfhi(us.w)), 0.f);
        uint4 o;
        o.x = packbf(h0, h1); o.y = packbf(h2, h3);
        o.z = packbf(h4, h5); o.w = packbf(h6, h7);
        *reinterpret_cast<uint4*>(&H[(size_t)node * 128 + l16 * 8]) = o;
    }
}

// ---------------- MFMA head: logits = H @ Wb^T (+bias), fused log_softmax ----------------
__global__ __launch_bounds__(256) void mlp_head_mfma(const unsigned short* __restrict__ H,
                                                     const unsigned short* __restrict__ Wb,
                                                     const float* __restrict__ bm,
                                                     float* __restrict__ out, int N) {
    __shared__ unsigned short sW[48 * 128];   // 12 KB
    int t = threadIdx.x;
    for (int i = t; i < 48 * 128 / 2; i += 256)
        ((unsigned*)sW)[i] = ((const unsigned*)Wb)[i];
    __syncthreads();

    const int wave = t >> 6, lane = t & 63;
    const int m0 = blockIdx.x * 64 + wave * 16;
    if (m0 >= N) return;
    const int r15 = lane & 15;
    const int k8  = (lane >> 4) * 8;
    const int arow = min(m0 + r15, N - 1);

    float4v acc[3] = {{0.f,0.f,0.f,0.f},{0.f,0.f,0.f,0.f},{0.f,0.f,0.f,0.f}};
    #pragma unroll
    for (int k0 = 0; k0 < 128; k0 += 32) {
        short8 a = *reinterpret_cast<const short8*>(&H[(size_t)arow * 128 + k0 + k8]);
        #pragma unroll
        for (int f = 0; f < 3; ++f) {
            short8 b = *reinterpret_cast<const short8*>(&sW[(f * 16 + r15) * 128 + k0 + k8]);
            acc[f] = __builtin_amdgcn_mfma_f32_16x16x32_bf16(a, b, acc[f], 0, 0, 0);
        }
    }

    float bias[3]; bool cv[3];
    #pragma unroll
    for (int f = 0; f < 3; ++f) {
        int c = f * 16 + r15;
        cv[f] = (c < NCLASS);
        bias[f] = cv[f] ? bm[c] : 0.f;
    }
    #pragma unroll
    for (int r = 0; r < 4; ++r) {
        int node = m0 + (lane >> 4) * 4 + r;
        float lg[3];
        float m = -1e30f;
        #pragma unroll
        for (int f = 0; f < 3; ++f) {
            lg[f] = cv[f] ? (acc[f][r] + bias[f]) : -1e30f;
            m = fmaxf(m, lg[f]);
        }
        m = fmaxf(m, __shfl_xor(m, 1));
        m = fmaxf(m, __shfl_xor(m, 2));
        m = fmaxf(m, __shfl_xor(m, 4));
        m = fmaxf(m, __shfl_xor(m, 8));
        float s = 0.f;
        #pragma unroll
        for (int f = 0; f < 3; ++f) s += cv[f] ? __expf(lg[f] - m) : 0.f;
        s += __shfl_xor(s, 1);
        s += __shfl_xor(s, 2);
        s += __shfl_xor(s, 4);
        s += __shfl_xor(s, 8);
        float ls = __logf(s);
        if (node < N) {
            #pragma unroll
            for (int f = 0; f < 3; ++f)
                if (cv[f]) out[(size_t)node * NCLASS + f * 16 + r15] = lg[f] - m - ls;
        }
    }
}

extern "C" void kernel_launch(void* const* d_in, const int* in_sizes, int n_in,
                              void* d_out, int out_size, void* d_ws, size_t ws_size,
                              hipStream_t stream) {
    const float* x    = (const float*)d_in[0];
    const float* W1   = (const float*)d_in[1];
    const float* W2   = (const float*)d_in[2];
    const float* mlpW = (const float*)d_in[3];
    const float* mlpb = (const float*)d_in[4];
    const int*   rows = (const int*)d_in[5];
    const int*   cols = (const int*)d_in[6];

    const int N = in_sizes[0] / NFEAT;   // 100000
    const int E = in_sizes[5];           // 3200000

    char* ws = (char*)d_ws;
    size_t off = 0;
    auto alloc = [&](size_t bytes) -> void* {
        void* p = ws + off;
        off = (off + bytes + 255) & ~(size_t)255;
        return p;
    };
    unsigned short* Xb  = (unsigned short*)alloc((size_t)N * 256 * 2);
    unsigned short* P   = (unsigned short*)alloc((size_t)N * 256 * 2);
    unsigned short* H   = (unsigned short*)alloc((size_t)N * 128 * 2);
    float* INV    = (float*)alloc((size_t)N * 4);
    int*   ROWP   = (int*)  alloc((size_t)(N + 1) * 4);
    int*   CSRC   = (int*)  alloc((size_t)E * 4);
    unsigned* BINNED = (unsigned*)alloc((size_t)E * 4);
    int*   GHIST  = (int*)  alloc((size_t)256 * 4);
    int*   GBASE  = (int*)  alloc((size_t)257 * 4);
    int*   GCUR   = (int*)  alloc((size_t)256 * 4);
    unsigned short* Wp1 = (unsigned short*)alloc((size_t)256 * 256 * 2);
    unsigned short* Wp2 = (unsigned short*)alloc((size_t)128 * 256 * 2);
    unsigned short* Wb  = (unsigned short*)alloc((size_t)48 * 128 * 2);

    const int nbuck = (N + 511) >> 9;              // 196
    const int nblk  = (E + TILE_E - 1) / TILE_E;   // 391

    // ---- CSR build via LDS-histogram binning (also produces row_ptr + inv_deg) ----
    hipMemsetAsync(GHIST, 0, 256 * 4, stream);
    bin_hist<<<nblk, 256, 0, stream>>>(rows, GHIST, E, nbuck);
    scan_buckets<<<1, 256, 0, stream>>>(GHIST, GBASE, GCUR, ROWP, nbuck, N, E);
    bin_scatter<<<nblk, 256, 0, stream>>>(rows, cols, GCUR, BINNED, E, nbuck);
    fill_win<<<nbuck, 256, 0, stream>>>(BINNED, GBASE, ROWP, INV, CSRC, N);

    // ---- dtype prep ----
    long long n4 = (long long)N * 256 / 4;
    conv_bf16<<<(int)((n4 + 255) / 256), 256, 0, stream>>>(x, Xb, n4);
    repack_all<<<560, 256, 0, stream>>>(W1, W2, mlpW, Wp1, Wp2, Wb);

    dim3 ggrid(2, (N + 127) / 128);
    const int gblocks = (int)(((long long)N * 64 + 255) / 256);

    // ---- layer 1 ----
    gemm_mfma<<<ggrid, 256, 0, stream>>>(Xb, Wp1, P, N, 256);
    gather_combine<<<gblocks, 256, 0, stream>>>(P, ROWP, CSRC, INV, H, N);

    // ---- layer 2 ----
    gemm_mfma<<<ggrid, 256, 0, stream>>>(H, Wp2, P, N, 128);
    gather_combine<<<gblocks, 256, 0, stream>>>(P, ROWP, CSRC, INV, H, N);

    // ---- head ----
    mlp_head_mfma<<<(N + 63) / 64, 256, 0, stream>>>(H, Wb, mlpb, (float*)d_out, N);
}

// Round 9
// 566.546 us; speedup vs baseline: 15.8119x; 1.0200x over previous
//
#include <hip/hip_runtime.h>
#include <hip/hip_bf16.h>

#define NFEAT 256
#define NHID  128
#define NCLASS 40

typedef __attribute__((ext_vector_type(8))) short short8;
typedef __attribute__((ext_vector_type(4))) float float4v;

__device__ __forceinline__ unsigned short f2bf(float f) {
    union { float f; unsigned u; } v; v.f = f;
    unsigned r = v.u + 0x7fff + ((v.u >> 16) & 1);   // RNE
    return (unsigned short)(r >> 16);
}
__device__ __forceinline__ float bflo(unsigned u) { return __uint_as_float(u << 16); }
__device__ __forceinline__ float bfhi(unsigned u) { return __uint_as_float(u & 0xffff0000u); }
__device__ __forceinline__ unsigned packbf(float a, float b) {
    return (unsigned)f2bf(a) | ((unsigned)f2bf(b) << 16);
}

// async global->LDS, 16B per lane; LDS dest = wave-uniform base + lane*16
__device__ __forceinline__ void ld_g2l16(const unsigned short* gp, unsigned short* lp) {
    __builtin_amdgcn_global_load_lds((const __attribute__((address_space(1))) unsigned short*)gp,
                                     (__attribute__((address_space(3))) unsigned short*)lp,
                                     16, 0, 0);
}

#define TILE_E 4096   // edges per binning block

// ---- K1: per-block LDS histogram of row>>9 buckets -> few global atomics ----
__global__ __launch_bounds__(256) void bin_hist(const int* __restrict__ rows,
                                                int* __restrict__ ghist, int E, int nbuck) {
    __shared__ int hh[256];
    int t = threadIdx.x;
    hh[t] = 0;
    __syncthreads();
    int e0 = blockIdx.x * TILE_E;
    #pragma unroll
    for (int it = 0; it < TILE_E / 1024; ++it) {
        int base = e0 + (it * 256 + t) * 4;
        if (base + 3 < E) {
            int4 v = *reinterpret_cast<const int4*>(&rows[base]);
            atomicAdd(&hh[v.x >> 9], 1);
            atomicAdd(&hh[v.y >> 9], 1);
            atomicAdd(&hh[v.z >> 9], 1);
            atomicAdd(&hh[v.w >> 9], 1);
        } else {
            for (int k = 0; k < 4; ++k)
                if (base + k < E) atomicAdd(&hh[rows[base + k] >> 9], 1);
        }
    }
    __syncthreads();
    if (t < nbuck && hh[t]) atomicAdd(&ghist[t], hh[t]);
}

// ---- K2: scan bucket counts -> bases + cursors; row_ptr[N] = E ----
__global__ void scan_buckets(const int* __restrict__ ghist, int* __restrict__ gbase,
                             int* __restrict__ gcur, int* __restrict__ row_ptr,
                             int nbuck, int N, int E) {
    __shared__ int s[256];
    int t = threadIdx.x;
    int v = (t < nbuck) ? ghist[t] : 0;
    s[t] = v;
    __syncthreads();
    for (int off = 1; off < 256; off <<= 1) {
        int tmp = (t >= off) ? s[t - off] : 0;
        __syncthreads();
        s[t] += tmp;
        __syncthreads();
    }
    int excl = s[t] - v;
    if (t < nbuck) { gbase[t] = excl; gcur[t] = excl; }
    if (t == 0) { gbase[nbuck] = E; row_ptr[N] = E; }
}

// ---- K3: re-histogram tile, reserve per-bucket chunks, scatter packed pairs ----
// packed entry: (row & 511) << 17 | col   (col < 2^17)
__global__ __launch_bounds__(256) void bin_scatter(const int* __restrict__ rows,
                                                   const int* __restrict__ cols,
                                                   int* __restrict__ gcur,
                                                   unsigned* __restrict__ binned, int E, int nbuck) {
    __shared__ int hh[256];
    __shared__ int lbase[256];
    __shared__ int lcur[256];
    int t = threadIdx.x;
    hh[t] = 0;
    __syncthreads();
    int e0 = blockIdx.x * TILE_E;
    #pragma unroll
    for (int it = 0; it < TILE_E / 1024; ++it) {
        int base = e0 + (it * 256 + t) * 4;
        if (base + 3 < E) {
            int4 v = *reinterpret_cast<const int4*>(&rows[base]);
            atomicAdd(&hh[v.x >> 9], 1);
            atomicAdd(&hh[v.y >> 9], 1);
            atomicAdd(&hh[v.z >> 9], 1);
            atomicAdd(&hh[v.w >> 9], 1);
        } else {
            for (int k = 0; k < 4; ++k)
                if (base + k < E) atomicAdd(&hh[rows[base + k] >> 9], 1);
        }
    }
    __syncthreads();
    if (t < nbuck) {
        lbase[t] = hh[t] ? atomicAdd(&gcur[t], hh[t]) : 0;
        lcur[t] = 0;
    }
    __syncthreads();
    #pragma unroll
    for (int it = 0; it < TILE_E / 1024; ++it) {
        int base = e0 + (it * 256 + t) * 4;
        if (base + 3 < E) {
            int4 r = *reinterpret_cast<const int4*>(&rows[base]);
            int4 c = *reinterpret_cast<const int4*>(&cols[base]);
            int b0 = r.x >> 9, b1 = r.y >> 9, b2 = r.z >> 9, b3 = r.w >> 9;
            int d0 = lbase[b0] + atomicAdd(&lcur[b0], 1);
            int d1 = lbase[b1] + atomicAdd(&lcur[b1], 1);
            int d2 = lbase[b2] + atomicAdd(&lcur[b2], 1);
            int d3 = lbase[b3] + atomicAdd(&lcur[b3], 1);
            binned[d0] = ((unsigned)(r.x & 511) << 17) | (unsigned)c.x;
            binned[d1] = ((unsigned)(r.y & 511) << 17) | (unsigned)c.y;
            binned[d2] = ((unsigned)(r.z & 511) << 17) | (unsigned)c.z;
            binned[d3] = ((unsigned)(r.w & 511) << 17) | (unsigned)c.w;
        } else {
            for (int k = 0; k < 4; ++k)
                if (base + k < E) {
                    int r = rows[base + k];
                    int b = r >> 9;
                    int dst = lbase[b] + atomicAdd(&lcur[b], 1);
                    binned[dst] = ((unsigned)(r & 511) << 17) | (unsigned)cols[base + k];
                }
        }
    }
}

// ---- K4: one block per 512-row window: degrees+scan -> row_ptr, inv_deg, CSR cols ----
__global__ __launch_bounds__(256) void fill_win(const unsigned* __restrict__ binned,
                                                const int* __restrict__ gbase,
                                                int* __restrict__ row_ptr,
                                                float* __restrict__ inv,
                                                int* __restrict__ csr_cols, int N) {
    __shared__ int h[512];
    __shared__ int ps[256];
    __shared__ int lcur[512];
    int t = threadIdx.x;
    int w = blockIdx.x;
    int r0 = w << 9;
    h[t] = 0; h[t + 256] = 0;
    __syncthreads();
    int beg = gbase[w], end = gbase[w + 1];
    for (int e = beg + t; e < end; e += 256)
        atomicAdd(&h[binned[e] >> 17], 1);
    __syncthreads();
    int pair = h[2 * t] + h[2 * t + 1];
    ps[t] = pair;
    __syncthreads();
    for (int off = 1; off < 256; off <<= 1) {
        int tmp = (t >= off) ? ps[t - off] : 0;
        __syncthreads();
        ps[t] += tmp;
        __syncthreads();
    }
    int base0 = beg + ps[t] - pair;
    int base1 = base0 + h[2 * t];
    int r_a = r0 + 2 * t, r_b = r0 + 2 * t + 1;
    if (r_a < N) { row_ptr[r_a] = base0; inv[r_a] = 1.0f / ((float)h[2 * t] + 1.0f); }
    if (r_b < N) { row_ptr[r_b] = base1; inv[r_b] = 1.0f / ((float)h[2 * t + 1] + 1.0f); }
    lcur[2 * t] = base0;
    lcur[2 * t + 1] = base1;
    __syncthreads();
    for (int e = beg + t; e < end; e += 256) {
        unsigned v = binned[e];
        int idx = atomicAdd(&lcur[v >> 17], 1);
        csr_cols[idx] = (int)(v & 0x1FFFFu);
    }
}

// ---------------- fused weight repack (W1, W2 -> K-panels; Wm -> padded bf16) ----------------
// Wp layout: [k0/32][o(256)][k(32)]
__global__ __launch_bounds__(256) void repack_all(const float* __restrict__ W1,
                                                  const float* __restrict__ W2,
                                                  const float* __restrict__ Wm,
                                                  unsigned short* __restrict__ Wp1,
                                                  unsigned short* __restrict__ Wp2,
                                                  unsigned short* __restrict__ Wb) {
    int b = blockIdx.x, t = threadIdx.x;
    if (b < 256) {                       // W1: o=b (0..255), k=t (0..255)
        float v = (b < 128) ? W1[b * 512 + t] : W1[(b - 128) * 512 + 256 + t];
        Wp1[(size_t)(t >> 5) * 256 * 32 + b * 32 + (t & 31)] = f2bf(v);
    } else if (b < 512) {                // W2: o=b-256 (0..255), k=t (0..127)
        int o = b - 256;
        if (t < 128) {
            float v = (o < 128) ? W2[o * 256 + t] : W2[(o - 128) * 256 + 128 + t];
            Wp2[(size_t)(t >> 5) * 256 * 32 + o * 32 + (t & 31)] = f2bf(v);
        }
    } else {                             // Wm: o=b-512 (0..47), k=t (0..127)
        int o = b - 512;
        if (t < 128) Wb[o * 128 + t] = (o < NCLASS) ? f2bf(Wm[o * 128 + t]) : 0;
    }
}

// ---------------- layer-1 GEMM: [PS|PN] = bf16(x[M x 256]) @ Wp1, fp32 A staged in-kernel ----
// BM=BN=128, BK=32; A via VGPR cvt + ds_write_b128; B via global_load_lds.
__global__ __launch_bounds__(256) void gemm1_mfma(const float* __restrict__ X,
                                                  const unsigned short* __restrict__ Wp,
                                                  unsigned short* __restrict__ PS,
                                                  unsigned short* __restrict__ PN,
                                                  int M) {
    __shared__ unsigned short sA[128 * 32];
    __shared__ unsigned short sB[128 * 32];
    const int t    = threadIdx.x;
    const int lane = t & 63;
    const int wave = t >> 6;
    const int m0 = blockIdx.y * 128;
    const int n0 = blockIdx.x * 128;      // 0 or 128
    const int wm = (wave >> 1) * 64;
    const int wn = (wave & 1) * 64;

    const int r15 = lane & 15;
    const int k8  = (lane >> 4) * 8;
    const int srow = lane >> 2;
    const int skb  = (lane & 3) * 8;

    float4v acc[4][4] = {{{0.f,0.f,0.f,0.f}}};

    for (int k0 = 0; k0 < 256; k0 += 32) {
        const unsigned short* pan = Wp + ((size_t)(k0 >> 5) * 256 + n0) * 32;
        #pragma unroll
        for (int it = 0; it < 2; ++it) {
            int slab = it * 64 + wave * 16;
            int gm = min(m0 + slab + srow, M - 1);    // clamp: x is an input alloc
            const float* gA = X + (size_t)gm * 256 + k0 + skb;
            float4 v0 = *reinterpret_cast<const float4*>(gA);
            float4 v1 = *reinterpret_cast<const float4*>(gA + 4);
            short8 av;
            av[0] = (short)f2bf(v0.x); av[1] = (short)f2bf(v0.y);
            av[2] = (short)f2bf(v0.z); av[3] = (short)f2bf(v0.w);
            av[4] = (short)f2bf(v1.x); av[5] = (short)f2bf(v1.y);
            av[6] = (short)f2bf(v1.z); av[7] = (short)f2bf(v1.w);
            *reinterpret_cast<short8*>(&sA[(slab + srow) * 32 + skb]) = av;
            const unsigned short* gB = pan + (size_t)(slab + srow) * 32 + skb;
            ld_g2l16(gB, &sB[slab * 32]);
        }
        __syncthreads();

        short8 aF[4], bF[4];
        #pragma unroll
        for (int i = 0; i < 4; ++i)
            aF[i] = *reinterpret_cast<const short8*>(&sA[(wm + i * 16 + r15) * 32 + k8]);
        #pragma unroll
        for (int j = 0; j < 4; ++j)
            bF[j] = *reinterpret_cast<const short8*>(&sB[(wn + j * 16 + r15) * 32 + k8]);
        #pragma unroll
        for (int i = 0; i < 4; ++i)
            #pragma unroll
            for (int j = 0; j < 4; ++j)
                acc[i][j] = __builtin_amdgcn_mfma_f32_16x16x32_bf16(aF[i], bF[j], acc[i][j], 0, 0, 0);
        __syncthreads();
    }

    unsigned short* out = (n0 == 0) ? PS : PN;
    #pragma unroll
    for (int i = 0; i < 4; ++i) {
        #pragma unroll
        for (int r = 0; r < 4; ++r) {
            int row = m0 + wm + i * 16 + (lane >> 4) * 4 + r;
            #pragma unroll
            for (int j = 0; j < 4; ++j) {
                float v  = acc[i][j][r];
                float vn = __shfl_xor(v, 1);
                if (row < M && !(r15 & 1))
                    *reinterpret_cast<unsigned*>(&out[(size_t)row * 128 + wn + j * 16 + r15]) = packbf(v, vn);
            }
        }
    }
}

// ---------------- layer-2 GEMM: [PS|PN] = H[M x 128] @ Wp2, async A+B staging ----------------
// A-tail of last M-block reads past H into adjacent ws regions — safe, store-masked.
__global__ __launch_bounds__(256) void gemm2_mfma(const unsigned short* __restrict__ H,
                                                  const unsigned short* __restrict__ Wp,
                                                  unsigned short* __restrict__ PS,
                                                  unsigned short* __restrict__ PN,
                                                  int M) {
    __shared__ unsigned short sA[128 * 32];
    __shared__ unsigned short sB[128 * 32];
    const int t    = threadIdx.x;
    const int lane = t & 63;
    const int wave = t >> 6;
    const int m0 = blockIdx.y * 128;
    const int n0 = blockIdx.x * 128;
    const int wm = (wave >> 1) * 64;
    const int wn = (wave & 1) * 64;

    const int r15 = lane & 15;
    const int k8  = (lane >> 4) * 8;
    const int srow = lane >> 2;
    const int skb  = (lane & 3) * 8;

    float4v acc[4][4] = {{{0.f,0.f,0.f,0.f}}};

    for (int k0 = 0; k0 < 128; k0 += 32) {
        const unsigned short* pan = Wp + ((size_t)(k0 >> 5) * 256 + n0) * 32;
        #pragma unroll
        for (int it = 0; it < 2; ++it) {
            int slab = it * 64 + wave * 16;
            const unsigned short* gA = H + (size_t)(m0 + slab + srow) * 128 + k0 + skb;
            ld_g2l16(gA, &sA[slab * 32]);
            const unsigned short* gB = pan + (size_t)(slab + srow) * 32 + skb;
            ld_g2l16(gB, &sB[slab * 32]);
        }
        __syncthreads();

        short8 aF[4], bF[4];
        #pragma unroll
        for (int i = 0; i < 4; ++i)
            aF[i] = *reinterpret_cast<const short8*>(&sA[(wm + i * 16 + r15) * 32 + k8]);
        #pragma unroll
        for (int j = 0; j < 4; ++j)
            bF[j] = *reinterpret_cast<const short8*>(&sB[(wn + j * 16 + r15) * 32 + k8]);
        #pragma unroll
        for (int i = 0; i < 4; ++i)
            #pragma unroll
            for (int j = 0; j < 4; ++j)
                acc[i][j] = __builtin_amdgcn_mfma_f32_16x16x32_bf16(aF[i], bF[j], acc[i][j], 0, 0, 0);
        __syncthreads();
    }

    unsigned short* out = (n0 == 0) ? PS : PN;
    #pragma unroll
    for (int i = 0; i < 4; ++i) {
        #pragma unroll
        for (int r = 0; r < 4; ++r) {
            int row = m0 + wm + i * 16 + (lane >> 4) * 4 + r;
            #pragma unroll
            for (int j = 0; j < 4; ++j) {
                float v  = acc[i][j][r];
                float vn = __shfl_xor(v, 1);
                if (row < M && !(r15 & 1))
                    *reinterpret_cast<unsigned*>(&out[(size_t)row * 128 + wn + j * 16 + r15]) = packbf(v, vn);
            }
        }
    }
}

// ---------------- gather-aggregate + combine + relu: one wave per node ----------------
// PN random-gather working set = 25.6MB (vs 51.2 when interleaved) -> better L2 hit rate.
__global__ __launch_bounds__(256) void gather_combine(const unsigned short* __restrict__ PS,
                                                      const unsigned short* __restrict__ PN,
                                                      const int* __restrict__ row_ptr,
                                                      const int* __restrict__ csr_cols,
                                                      const float* __restrict__ invdeg,
                                                      unsigned short* __restrict__ H, int N) {
    int node = (blockIdx.x * blockDim.x + threadIdx.x) >> 6;
    if (node >= N) return;
    int lane = threadIdx.x & 63;
    int grp  = lane >> 4;
    int l16  = lane & 15;
    int beg = row_ptr[node], end = row_ptr[node + 1];

    float a0=0,a1=0,a2=0,a3=0,a4=0,a5=0,a6=0,a7=0;
    int p0 = beg + grp;
    for (; p0 + 12 < end; p0 += 16) {
        int cA = csr_cols[p0];
        int cB = csr_cols[p0 + 4];
        int cC = csr_cols[p0 + 8];
        int cD = csr_cols[p0 + 12];
        uint4 uA = *reinterpret_cast<const uint4*>(&PN[(size_t)cA * 128 + l16 * 8]);
        uint4 uB = *reinterpret_cast<const uint4*>(&PN[(size_t)cB * 128 + l16 * 8]);
        uint4 uC = *reinterpret_cast<const uint4*>(&PN[(size_t)cC * 128 + l16 * 8]);
        uint4 uD = *reinterpret_cast<const uint4*>(&PN[(size_t)cD * 128 + l16 * 8]);
        a0 += bflo(uA.x) + bflo(uB.x) + bflo(uC.x) + bflo(uD.x);
        a1 += bfhi(uA.x) + bfhi(uB.x) + bfhi(uC.x) + bfhi(uD.x);
        a2 += bflo(uA.y) + bflo(uB.y) + bflo(uC.y) + bflo(uD.y);
        a3 += bfhi(uA.y) + bfhi(uB.y) + bfhi(uC.y) + bfhi(uD.y);
        a4 += bflo(uA.z) + bflo(uB.z) + bflo(uC.z) + bflo(uD.z);
        a5 += bfhi(uA.z) + bfhi(uB.z) + bfhi(uC.z) + bfhi(uD.z);
        a6 += bflo(uA.w) + bflo(uB.w) + bflo(uC.w) + bflo(uD.w);
        a7 += bfhi(uA.w) + bfhi(uB.w) + bfhi(uC.w) + bfhi(uD.w);
    }
    for (; p0 < end; p0 += 4) {
        int c = csr_cols[p0];
        uint4 u = *reinterpret_cast<const uint4*>(&PN[(size_t)c * 128 + l16 * 8]);
        a0 += bflo(u.x); a1 += bfhi(u.x);
        a2 += bflo(u.y); a3 += bfhi(u.y);
        a4 += bflo(u.z); a5 += bfhi(u.z);
        a6 += bflo(u.w); a7 += bfhi(u.w);
    }
    a0 += __shfl_xor(a0, 16); a1 += __shfl_xor(a1, 16);
    a2 += __shfl_xor(a2, 16); a3 += __shfl_xor(a3, 16);
    a4 += __shfl_xor(a4, 16); a5 += __shfl_xor(a5, 16);
    a6 += __shfl_xor(a6, 16); a7 += __shfl_xor(a7, 16);
    a0 += __shfl_xor(a0, 32); a1 += __shfl_xor(a1, 32);
    a2 += __shfl_xor(a2, 32); a3 += __shfl_xor(a3, 32);
    a4 += __shfl_xor(a4, 32); a5 += __shfl_xor(a5, 32);
    a6 += __shfl_xor(a6, 32); a7 += __shfl_xor(a7, 32);

    if (grp == 0) {
        float id = invdeg[node];
        uint4 us = *reinterpret_cast<const uint4*>(&PS[(size_t)node * 128 + l16 * 8]);
        float h0 = fmaxf(fmaf(a0, id, bflo(us.x)), 0.f);
        float h1 = fmaxf(fmaf(a1, id, bfhi(us.x)), 0.f);
        float h2 = fmaxf(fmaf(a2, id, bflo(us.y)), 0.f);
        float h3 = fmaxf(fmaf(a3, id, bfhi(us.y)), 0.f);
        float h4 = fmaxf(fmaf(a4, id, bflo(us.z)), 0.f);
        float h5 = fmaxf(fmaf(a5, id, bfhi(us.z)), 0.f);
        float h6 = fmaxf(fmaf(a6, id, bflo(us.w)), 0.f);
        float h7 = fmaxf(fmaf(a7, id, bfhi(us.w)), 0.f);
        uint4 o;
        o.x = packbf(h0, h1); o.y = packbf(h2, h3);
        o.z = packbf(h4, h5); o.w = packbf(h6, h7);
        *reinterpret_cast<uint4*>(&H[(size_t)node * 128 + l16 * 8]) = o;
    }
}

// ---------------- MFMA head: logits = H @ Wb^T (+bias), fused log_softmax ----------------
__global__ __launch_bounds__(256) void mlp_head_mfma(const unsigned short* __restrict__ H,
                                                     const unsigned short* __restrict__ Wb,
                                                     const float* __restrict__ bm,
                                                     float* __restrict__ out, int N) {
    __shared__ unsigned short sW[48 * 128];   // 12 KB
    int t = threadIdx.x;
    for (int i = t; i < 48 * 128 / 2; i += 256)
        ((unsigned*)sW)[i] = ((const unsigned*)Wb)[i];
    __syncthreads();

    const int wave = t >> 6, lane = t & 63;
    const int m0 = blockIdx.x * 64 + wave * 16;
    if (m0 >= N) return;
    const int r15 = lane & 15;
    const int k8  = (lane >> 4) * 8;
    const int arow = min(m0 + r15, N - 1);

    float4v acc[3] = {{0.f,0.f,0.f,0.f},{0.f,0.f,0.f,0.f},{0.f,0.f,0.f,0.f}};
    #pragma unroll
    for (int k0 = 0; k0 < 128; k0 += 32) {
        short8 a = *reinterpret_cast<const short8*>(&H[(size_t)arow * 128 + k0 + k8]);
        #pragma unroll
        for (int f = 0; f < 3; ++f) {
            short8 b = *reinterpret_cast<const short8*>(&sW[(f * 16 + r15) * 128 + k0 + k8]);
            acc[f] = __builtin_amdgcn_mfma_f32_16x16x32_bf16(a, b, acc[f], 0, 0, 0);
        }
    }

    float bias[3]; bool cv[3];
    #pragma unroll
    for (int f = 0; f < 3; ++f) {
        int c = f * 16 + r15;
        cv[f] = (c < NCLASS);
        bias[f] = cv[f] ? bm[c] : 0.f;
    }
    #pragma unroll
    for (int r = 0; r < 4; ++r) {
        int node = m0 + (lane >> 4) * 4 + r;
        float lg[3];
        float m = -1e30f;
        #pragma unroll
        for (int f = 0; f < 3; ++f) {
            lg[f] = cv[f] ? (acc[f][r] + bias[f]) : -1e30f;
            m = fmaxf(m, lg[f]);
        }
        m = fmaxf(m, __shfl_xor(m, 1));
        m = fmaxf(m, __shfl_xor(m, 2));
        m = fmaxf(m, __shfl_xor(m, 4));
        m = fmaxf(m, __shfl_xor(m, 8));
        float s = 0.f;
        #pragma unroll
        for (int f = 0; f < 3; ++f) s += cv[f] ? __expf(lg[f] - m) : 0.f;
        s += __shfl_xor(s, 1);
        s += __shfl_xor(s, 2);
        s += __shfl_xor(s, 4);
        s += __shfl_xor(s, 8);
        float ls = __logf(s);
        if (node < N) {
            #pragma unroll
            for (int f = 0; f < 3; ++f)
                if (cv[f]) out[(size_t)node * NCLASS + f * 16 + r15] = lg[f] - m - ls;
        }
    }
}

extern "C" void kernel_launch(void* const* d_in, const int* in_sizes, int n_in,
                              void* d_out, int out_size, void* d_ws, size_t ws_size,
                              hipStream_t stream) {
    const float* x    = (const float*)d_in[0];
    const float* W1   = (const float*)d_in[1];
    const float* W2   = (const float*)d_in[2];
    const float* mlpW = (const float*)d_in[3];
    const float* mlpb = (const float*)d_in[4];
    const int*   rows = (const int*)d_in[5];
    const int*   cols = (const int*)d_in[6];

    const int N = in_sizes[0] / NFEAT;   // 100000
    const int E = in_sizes[5];           // 3200000

    char* ws = (char*)d_ws;
    size_t off = 0;
    auto alloc = [&](size_t bytes) -> void* {
        void* p = ws + off;
        off = (off + bytes + 255) & ~(size_t)255;
        return p;
    };
    unsigned short* PS  = (unsigned short*)alloc((size_t)N * 128 * 2);  // self-projection
    unsigned short* PN  = (unsigned short*)alloc((size_t)N * 128 * 2);  // neigh-projection
    unsigned short* H   = (unsigned short*)alloc((size_t)N * 128 * 2);  // hidden
    float* INV    = (float*)alloc((size_t)N * 4);
    int*   ROWP   = (int*)  alloc((size_t)(N + 1) * 4);
    int*   CSRC   = (int*)  alloc((size_t)E * 4);
    unsigned* BINNED = (unsigned*)alloc((size_t)E * 4);
    int*   GHIST  = (int*)  alloc((size_t)256 * 4);
    int*   GBASE  = (int*)  alloc((size_t)257 * 4);
    int*   GCUR   = (int*)  alloc((size_t)256 * 4);
    unsigned short* Wp1 = (unsigned short*)alloc((size_t)256 * 256 * 2);
    unsigned short* Wp2 = (unsigned short*)alloc((size_t)128 * 256 * 2);
    unsigned short* Wb  = (unsigned short*)alloc((size_t)48 * 128 * 2);

    const int nbuck = (N + 511) >> 9;              // 196
    const int nblk  = (E + TILE_E - 1) / TILE_E;   // 782

    // ---- CSR build via LDS-histogram binning (also produces row_ptr + inv_deg) ----
    hipMemsetAsync(GHIST, 0, 256 * 4, stream);
    bin_hist<<<nblk, 256, 0, stream>>>(rows, GHIST, E, nbuck);
    scan_buckets<<<1, 256, 0, stream>>>(GHIST, GBASE, GCUR, ROWP, nbuck, N, E);
    bin_scatter<<<nblk, 256, 0, stream>>>(rows, cols, GCUR, BINNED, E, nbuck);
    fill_win<<<nbuck, 256, 0, stream>>>(BINNED, GBASE, ROWP, INV, CSRC, N);

    // ---- weight prep ----
    repack_all<<<560, 256, 0, stream>>>(W1, W2, mlpW, Wp1, Wp2, Wb);

    dim3 ggrid(2, (N + 127) / 128);
    const int gblocks = (int)(((long long)N * 64 + 255) / 256);

    // ---- layer 1 (reads fp32 x directly, converts in staging) ----
    gemm1_mfma<<<ggrid, 256, 0, stream>>>(x, Wp1, PS, PN, N);
    gather_combine<<<gblocks, 256, 0, stream>>>(PS, PN, ROWP, CSRC, INV, H, N);

    // ---- layer 2 ----
    gemm2_mfma<<<ggrid, 256, 0, stream>>>(H, Wp2, PS, PN, N);
    gather_combine<<<gblocks, 256, 0, stream>>>(PS, PN, ROWP, CSRC, INV, H, N);

    // ---- head ----
    mlp_head_mfma<<<(N + 63) / 64, 256, 0, stream>>>(H, Wb, mlpb, (float*)d_out, N);
}